// Round 1
// baseline (2008.655 us; speedup 1.0000x reference)
//
#include <hip/hip_runtime.h>
#include <hip/hip_bf16.h>

namespace {

constexpr int kT = 4096;
constexpr int kHid = 1024;
constexpr int kNH = 8;
constexpr int kHS = 128;
constexpr int kNSlots = 8192;
constexpr float kEps = 1e-6f;
constexpr float kScale = 0.08838834764831845f;  // 128^-0.5
constexpr float kNeg = -1e30f;

// ---------------------------------------------------------------------------
// QKV GEMM: qkv[t, c] = sum_k H[t,k] * Wqkv[c,k];  C tile 64 rows x 128 cols.
// Col chunk bc: 0..7 -> q head bc; 8..15 -> k head bc-8; 16..23 -> v head.
// Epilogue fuses l2norm (per row over the 128-col chunk) + RoPE and scatters
// k/v into the output caches; q goes to qbuf.
// ---------------------------------------------------------------------------
__global__ __launch_bounds__(256)
void qkv_gemm_kernel(const float* __restrict__ H, const float* __restrict__ W,
                     const float* __restrict__ cosb, const float* __restrict__ sinb,
                     const int* __restrict__ slots,
                     float* __restrict__ qbuf, float* __restrict__ ock,
                     float* __restrict__ ocv) {
  __shared__ float As[16][68];    // k-major: As[kk][row]
  __shared__ float Bs[16][136];   // k-major: Bs[kk][col]
  const int row0 = blockIdx.x * 64;
  const int bc = blockIdx.y;
  const int col0 = bc * 128;
  const int tid = threadIdx.x;
  const int tx = tid & 15, ty = tid >> 4;

  float acc[4][8];
#pragma unroll
  for (int i = 0; i < 4; ++i)
#pragma unroll
    for (int j = 0; j < 8; ++j) acc[i][j] = 0.f;

  const int ar = tid >> 2, ak = (tid & 3) << 2;  // A stage: row, k-offset
  const int br = tid >> 1, bk = (tid & 1) << 3;  // B stage: row, k-offset
  const float* aptr = H + (size_t)(row0 + ar) * kHid + ak;
  const float* bptr = W + (size_t)(col0 + br) * kHid + bk;

  for (int k0 = 0; k0 < kHid; k0 += 16) {
    const float4 av = *(const float4*)(aptr + k0);
    const float4 bv0 = *(const float4*)(bptr + k0);
    const float4 bv1 = *(const float4*)(bptr + k0 + 4);
    __syncthreads();
    As[ak + 0][ar] = av.x; As[ak + 1][ar] = av.y;
    As[ak + 2][ar] = av.z; As[ak + 3][ar] = av.w;
    Bs[bk + 0][br] = bv0.x; Bs[bk + 1][br] = bv0.y;
    Bs[bk + 2][br] = bv0.z; Bs[bk + 3][br] = bv0.w;
    Bs[bk + 4][br] = bv1.x; Bs[bk + 5][br] = bv1.y;
    Bs[bk + 6][br] = bv1.z; Bs[bk + 7][br] = bv1.w;
    __syncthreads();
#pragma unroll
    for (int kk = 0; kk < 16; ++kk) {
      const float4 a = *(const float4*)&As[kk][ty * 4];
      const float4 b0 = *(const float4*)&Bs[kk][tx * 8];
      const float4 b1 = *(const float4*)&Bs[kk][tx * 8 + 4];
      const float aa[4] = {a.x, a.y, a.z, a.w};
      const float bb[8] = {b0.x, b0.y, b0.z, b0.w, b1.x, b1.y, b1.z, b1.w};
#pragma unroll
      for (int i = 0; i < 4; ++i)
#pragma unroll
        for (int j = 0; j < 8; ++j) acc[i][j] = fmaf(aa[i], bb[j], acc[i][j]);
    }
  }

  // Epilogue. Thread owns rows row0+ty*4+i, cols tx*8+j (within the 128-chunk).
  if (bc < 16) {
    // l2norm over the 128 cols of this chunk, per row.
    float rs[4];
#pragma unroll
    for (int i = 0; i < 4; ++i) {
      float ss = 0.f;
#pragma unroll
      for (int j = 0; j < 8; ++j) ss = fmaf(acc[i][j], acc[i][j], ss);
      ss += __shfl_xor(ss, 1);
      ss += __shfl_xor(ss, 2);
      ss += __shfl_xor(ss, 4);
      ss += __shfl_xor(ss, 8);
      rs[i] = rsqrtf(ss * (1.f / 128.f) + kEps);
    }
    const int h = bc & 7;
    const bool isq = (bc < 8);
#pragma unroll
    for (int i = 0; i < 4; ++i) {
      const int t = row0 + ty * 4 + i;
      float cc[4], ssn[4];
#pragma unroll
      for (int jj = 0; jj < 4; ++jj) {
        cc[jj] = cosb[t * 64 + tx * 4 + jj];
        ssn[jj] = sinb[t * 64 + tx * 4 + jj];
      }
      float o[8];
#pragma unroll
      for (int jj = 0; jj < 4; ++jj) {
        const float xr = acc[i][2 * jj] * rs[i];
        const float xi = acc[i][2 * jj + 1] * rs[i];
        o[2 * jj] = xr * cc[jj] - xi * ssn[jj];
        o[2 * jj + 1] = xr * ssn[jj] + xi * cc[jj];
      }
      float* dst;
      if (isq) {
        dst = qbuf + (size_t)t * kHid + h * kHS + tx * 8;
      } else {
        dst = ock + (size_t)slots[t] * (kNH * kHS) + h * kHS + tx * 8;
      }
      *(float4*)dst = make_float4(o[0], o[1], o[2], o[3]);
      *((float4*)dst + 1) = make_float4(o[4], o[5], o[6], o[7]);
    }
  } else {
    const int h = bc - 16;
#pragma unroll
    for (int i = 0; i < 4; ++i) {
      const int t = row0 + ty * 4 + i;
      float* dst = ocv + (size_t)slots[t] * (kNH * kHS) + h * kHS + tx * 8;
      *(float4*)dst = make_float4(acc[i][0], acc[i][1], acc[i][2], acc[i][3]);
      *((float4*)dst + 1) = make_float4(acc[i][4], acc[i][5], acc[i][6], acc[i][7]);
    }
  }
}

// ---------------------------------------------------------------------------
// Flash attention: block = (q-tile of 64 rows, head). Online softmax.
// S cols mapped as c = j*16+tx (conflict-free K reads); O cols as c = tx*8+jo.
// ---------------------------------------------------------------------------
__global__ __launch_bounds__(256)
void attn_kernel(const float* __restrict__ qbuf, const float* __restrict__ ock,
                 const float* __restrict__ ocv, const int* __restrict__ slots,
                 float* __restrict__ abuf) {
  __shared__ float Qs[64][132];
  __shared__ float Ks[64][132];
  __shared__ float Vs[64][132];
  __shared__ float Ps[64][68];
  const int qt = blockIdx.x;
  const int h = blockIdx.y;
  const int q0 = qt * 64;
  const int tid = threadIdx.x;
  const int tx = tid & 15, ty = tid >> 4;

  // Stage Q tile (pre-scaled by 1/sqrt(HS)).
  for (int it = tid; it < 64 * 32; it += 256) {
    const int r = it >> 5;
    const int c4 = (it & 31) << 2;
    float4 v = *(const float4*)&qbuf[(size_t)(q0 + r) * kHid + h * kHS + c4];
    v.x *= kScale; v.y *= kScale; v.z *= kScale; v.w *= kScale;
    *(float4*)&Qs[r][c4] = v;
  }

  float m[4], l[4], o[4][8];
#pragma unroll
  for (int i = 0; i < 4; ++i) {
    m[i] = kNeg;
    l[i] = 0.f;
#pragma unroll
    for (int jo = 0; jo < 8; ++jo) o[i][jo] = 0.f;
  }

  for (int j0 = 0; j0 <= q0; j0 += 64) {
    __syncthreads();  // previous tile's Ps/Vs reads done; Qs ready (1st iter)
    for (int it = tid; it < 64 * 32; it += 256) {
      const int r = it >> 5;
      const int c4 = (it & 31) << 2;
      const int slot = slots[j0 + r];
      const size_t base = (size_t)slot * (kNH * kHS) + h * kHS + c4;
      *(float4*)&Ks[r][c4] = *(const float4*)&ock[base];
      *(float4*)&Vs[r][c4] = *(const float4*)&ocv[base];
    }
    __syncthreads();

    // S = (Q*scale) K^T, rows ty*4+i, cols j*16+tx.
    float sv[4][4];
#pragma unroll
    for (int i = 0; i < 4; ++i)
#pragma unroll
      for (int j = 0; j < 4; ++j) sv[i][j] = 0.f;
    for (int d = 0; d < kHS; d += 4) {
      float4 qv[4], kv[4];
#pragma unroll
      for (int i = 0; i < 4; ++i) qv[i] = *(const float4*)&Qs[ty * 4 + i][d];
#pragma unroll
      for (int j = 0; j < 4; ++j) kv[j] = *(const float4*)&Ks[j * 16 + tx][d];
#pragma unroll
      for (int i = 0; i < 4; ++i)
#pragma unroll
        for (int j = 0; j < 4; ++j) {
          sv[i][j] = fmaf(qv[i].x, kv[j].x, sv[i][j]);
          sv[i][j] = fmaf(qv[i].y, kv[j].y, sv[i][j]);
          sv[i][j] = fmaf(qv[i].z, kv[j].z, sv[i][j]);
          sv[i][j] = fmaf(qv[i].w, kv[j].w, sv[i][j]);
        }
    }

    // Causal mask + online softmax.
#pragma unroll
    for (int i = 0; i < 4; ++i) {
      const int qrow = q0 + ty * 4 + i;
#pragma unroll
      for (int j = 0; j < 4; ++j) {
        const int kt = j0 + j * 16 + tx;
        if (kt > qrow) sv[i][j] = kNeg;
      }
      float mx = fmaxf(fmaxf(sv[i][0], sv[i][1]), fmaxf(sv[i][2], sv[i][3]));
      mx = fmaxf(mx, __shfl_xor(mx, 1));
      mx = fmaxf(mx, __shfl_xor(mx, 2));
      mx = fmaxf(mx, __shfl_xor(mx, 4));
      mx = fmaxf(mx, __shfl_xor(mx, 8));
      const float mnew = fmaxf(m[i], mx);
      const float alpha = __expf(m[i] - mnew);
      float ps = 0.f;
#pragma unroll
      for (int j = 0; j < 4; ++j) {
        const float p = __expf(sv[i][j] - mnew);
        ps += p;
        Ps[ty * 4 + i][j * 16 + tx] = p;
      }
      ps += __shfl_xor(ps, 1);
      ps += __shfl_xor(ps, 2);
      ps += __shfl_xor(ps, 4);
      ps += __shfl_xor(ps, 8);
      l[i] = l[i] * alpha + ps;
      m[i] = mnew;
#pragma unroll
      for (int jo = 0; jo < 8; ++jo) o[i][jo] *= alpha;
    }
    __syncthreads();

    // O += P V ; O cols tx*8+jo.
#pragma unroll 4
    for (int k = 0; k < 64; ++k) {
      const float p0 = Ps[ty * 4 + 0][k];
      const float p1 = Ps[ty * 4 + 1][k];
      const float p2 = Ps[ty * 4 + 2][k];
      const float p3 = Ps[ty * 4 + 3][k];
      const float4 va = *(const float4*)&Vs[k][tx * 8];
      const float4 vb = *(const float4*)&Vs[k][tx * 8 + 4];
      const float vv[8] = {va.x, va.y, va.z, va.w, vb.x, vb.y, vb.z, vb.w};
#pragma unroll
      for (int jo = 0; jo < 8; ++jo) {
        o[0][jo] = fmaf(p0, vv[jo], o[0][jo]);
        o[1][jo] = fmaf(p1, vv[jo], o[1][jo]);
        o[2][jo] = fmaf(p2, vv[jo], o[2][jo]);
        o[3][jo] = fmaf(p3, vv[jo], o[3][jo]);
      }
    }
  }

#pragma unroll
  for (int i = 0; i < 4; ++i) {
    const float inv = 1.f / l[i];
    const int t = q0 + ty * 4 + i;
    float* dst = abuf + (size_t)t * kHid + h * kHS + tx * 8;
    *(float4*)dst = make_float4(o[i][0] * inv, o[i][1] * inv, o[i][2] * inv, o[i][3] * inv);
    *((float4*)dst + 1) = make_float4(o[i][4] * inv, o[i][5] * inv, o[i][6] * inv, o[i][7] * inv);
  }
}

// ---------------------------------------------------------------------------
// Output GEMM: out[t, n] = sum_j attn[t, j] * Wo[n, j].
// ---------------------------------------------------------------------------
__global__ __launch_bounds__(256)
void out_gemm_kernel(const float* __restrict__ A, const float* __restrict__ W,
                     float* __restrict__ C) {
  __shared__ float As[16][68];
  __shared__ float Bs[16][136];
  const int row0 = blockIdx.x * 64;
  const int col0 = blockIdx.y * 128;
  const int tid = threadIdx.x;
  const int tx = tid & 15, ty = tid >> 4;

  float acc[4][8];
#pragma unroll
  for (int i = 0; i < 4; ++i)
#pragma unroll
    for (int j = 0; j < 8; ++j) acc[i][j] = 0.f;

  const int ar = tid >> 2, ak = (tid & 3) << 2;
  const int br = tid >> 1, bk = (tid & 1) << 3;
  const float* aptr = A + (size_t)(row0 + ar) * kHid + ak;
  const float* bptr = W + (size_t)(col0 + br) * kHid + bk;

  for (int k0 = 0; k0 < kHid; k0 += 16) {
    const float4 av = *(const float4*)(aptr + k0);
    const float4 bv0 = *(const float4*)(bptr + k0);
    const float4 bv1 = *(const float4*)(bptr + k0 + 4);
    __syncthreads();
    As[ak + 0][ar] = av.x; As[ak + 1][ar] = av.y;
    As[ak + 2][ar] = av.z; As[ak + 3][ar] = av.w;
    Bs[bk + 0][br] = bv0.x; Bs[bk + 1][br] = bv0.y;
    Bs[bk + 2][br] = bv0.z; Bs[bk + 3][br] = bv0.w;
    Bs[bk + 4][br] = bv1.x; Bs[bk + 5][br] = bv1.y;
    Bs[bk + 6][br] = bv1.z; Bs[bk + 7][br] = bv1.w;
    __syncthreads();
#pragma unroll
    for (int kk = 0; kk < 16; ++kk) {
      const float4 a = *(const float4*)&As[kk][ty * 4];
      const float4 b0 = *(const float4*)&Bs[kk][tx * 8];
      const float4 b1 = *(const float4*)&Bs[kk][tx * 8 + 4];
      const float aa[4] = {a.x, a.y, a.z, a.w};
      const float bb[8] = {b0.x, b0.y, b0.z, b0.w, b1.x, b1.y, b1.z, b1.w};
#pragma unroll
      for (int i = 0; i < 4; ++i)
#pragma unroll
        for (int j = 0; j < 8; ++j) acc[i][j] = fmaf(aa[i], bb[j], acc[i][j]);
    }
  }

#pragma unroll
  for (int i = 0; i < 4; ++i) {
    const int row = row0 + ty * 4 + i;
    float* dst = C + (size_t)row * kHid + col0 + tx * 8;
    *(float4*)dst = make_float4(acc[i][0], acc[i][1], acc[i][2], acc[i][3]);
    *((float4*)dst + 1) = make_float4(acc[i][4], acc[i][5], acc[i][6], acc[i][7]);
  }
}

}  // namespace

extern "C" void kernel_launch(void* const* d_in, const int* in_sizes, int n_in,
                              void* d_out, int out_size, void* d_ws, size_t ws_size,
                              hipStream_t stream) {
  (void)in_sizes; (void)n_in; (void)out_size; (void)ws_size;
  const float* H = (const float*)d_in[0];
  const float* cosb = (const float*)d_in[1];
  const float* sinb = (const float*)d_in[2];
  const float* Wqkv = (const float*)d_in[3];
  const float* Wo = (const float*)d_in[4];
  const int* slots = (const int*)d_in[5];
  const float* ck = (const float*)d_in[6];
  const float* cv = (const float*)d_in[7];

  float* out = (float*)d_out;
  float* ock = out + (size_t)kT * kHid;                 // new_cache_k
  float* ocv = ock + (size_t)kNSlots * kNH * kHS;       // new_cache_v
  float* qbuf = out;          // stash q in the (not-yet-written) out region
  float* abuf = (float*)d_ws; // attention output (16 MiB)

  const size_t cache_bytes = (size_t)kNSlots * kNH * kHS * sizeof(float);
  hipMemcpyAsync(ock, ck, cache_bytes, hipMemcpyDeviceToDevice, stream);
  hipMemcpyAsync(ocv, cv, cache_bytes, hipMemcpyDeviceToDevice, stream);

  qkv_gemm_kernel<<<dim3(kT / 64, 24), 256, 0, stream>>>(
      H, Wqkv, cosb, sinb, slots, qbuf, ock, ocv);
  attn_kernel<<<dim3(kT / 64, kNH), 256, 0, stream>>>(
      qbuf, ock, ocv, slots, abuf);
  out_gemm_kernel<<<dim3(kT / 64, kHid / 128), 256, 0, stream>>>(
      abuf, Wo, out);
}

// Round 2
// 342.479 us; speedup vs baseline: 5.8650x; 5.8650x over previous
//
#include <hip/hip_runtime.h>
#include <hip/hip_bf16.h>

namespace {

constexpr int kT = 4096;
constexpr int kHid = 1024;
constexpr int kNH = 8;
constexpr int kHS = 128;
constexpr int kNSlots = 8192;
constexpr float kEps = 1e-6f;
constexpr float kScale = 0.08838834764831845f;  // 128^-0.5
constexpr float kNeg = -1e30f;

typedef __attribute__((ext_vector_type(8))) short bf16x8;
typedef __attribute__((ext_vector_type(4))) float f32x4;

__device__ __forceinline__ short f2bf(float x) {
  unsigned u = __builtin_bit_cast(unsigned, x);
  unsigned r = (u + 0x7FFFu + ((u >> 16) & 1u)) >> 16;
  return (short)r;
}

__device__ __forceinline__ bf16x8 pack_bf8(float4 a, float4 b) {
  bf16x8 r;
  r[0] = f2bf(a.x); r[1] = f2bf(a.y); r[2] = f2bf(a.z); r[3] = f2bf(a.w);
  r[4] = f2bf(b.x); r[5] = f2bf(b.y); r[6] = f2bf(b.z); r[7] = f2bf(b.w);
  return r;
}

// 16B-slot XOR swizzle for [row][32 bf16] LDS tiles (64B rows): keeps
// ds_read_b128 fragment loads at 2-way bank aliasing (free per m136).
__device__ __forceinline__ int swz(int r) { return ((r >> 1) ^ (r >> 3)) & 3; }

__device__ __forceinline__ void stage16(short* tile, int r, int k0,
                                        float4 a, float4 b, float4 c, float4 d) {
  const int sw = swz(r);
  const int s0 = k0 >> 3;  // 0 or 2
  *(bf16x8*)&tile[r * 32 + (((s0 + 0) ^ sw) << 3)] = pack_bf8(a, b);
  *(bf16x8*)&tile[r * 32 + (((s0 + 1) ^ sw) << 3)] = pack_bf8(c, d);
}

// ---------------------------------------------------------------------------
// QKV GEMM (bf16 MFMA): tile 128 rows(t) x 128 cols, BK=32. 4 waves stacked:
// wave w owns rows w*32..w*32+31 (2 row-tiles x 8 col-tiles of 16x16).
// Epilogue: l2norm + RoPE (q/k), scatter k/v f32 into caches, emit bf16
// Q (pre-scaled), K, V buffers for attention.
// ---------------------------------------------------------------------------
__global__ __launch_bounds__(256)
void qkv_gemm_kernel(const float* __restrict__ H, const float* __restrict__ W,
                     const float* __restrict__ cosb, const float* __restrict__ sinb,
                     const int* __restrict__ slots,
                     short* __restrict__ Qb, short* __restrict__ Kb,
                     short* __restrict__ Vb,
                     float* __restrict__ ock, float* __restrict__ ocv) {
  __shared__ short As[128 * 32];
  __shared__ short Bs[128 * 32];
  const int row0 = blockIdx.x * 128;
  const int bc = blockIdx.y;            // 0..7 q, 8..15 k, 16..23 v
  const int col0 = bc * 128;
  const int tid = threadIdx.x;
  const int lane = tid & 63, w = tid >> 6;
  const int lm = lane & 15, lg = lane >> 4;
  const int r_st = tid >> 1, k_st = (tid & 1) * 16;

  f32x4 acc[2][8];
#pragma unroll
  for (int rt = 0; rt < 2; ++rt)
#pragma unroll
    for (int ct = 0; ct < 8; ++ct) acc[rt][ct] = (f32x4){0.f, 0.f, 0.f, 0.f};

  const float* ap = H + (size_t)(row0 + r_st) * kHid + k_st;
  const float* bp = W + (size_t)(col0 + r_st) * kHid + k_st;
  const int arow0 = w * 32 + lm, arow1 = w * 32 + 16 + lm;

  for (int k0 = 0; k0 < kHid; k0 += 32) {
    const float4 a0 = *(const float4*)(ap + k0);
    const float4 a1 = *(const float4*)(ap + k0 + 4);
    const float4 a2 = *(const float4*)(ap + k0 + 8);
    const float4 a3 = *(const float4*)(ap + k0 + 12);
    const float4 b0 = *(const float4*)(bp + k0);
    const float4 b1 = *(const float4*)(bp + k0 + 4);
    const float4 b2 = *(const float4*)(bp + k0 + 8);
    const float4 b3 = *(const float4*)(bp + k0 + 12);
    __syncthreads();
    stage16(As, r_st, k_st, a0, a1, a2, a3);
    stage16(Bs, r_st, k_st, b0, b1, b2, b3);
    __syncthreads();
    const bf16x8 af0 = *(const bf16x8*)&As[arow0 * 32 + ((lg ^ swz(arow0)) << 3)];
    const bf16x8 af1 = *(const bf16x8*)&As[arow1 * 32 + ((lg ^ swz(arow1)) << 3)];
#pragma unroll
    for (int ct = 0; ct < 8; ++ct) {
      const int brow = ct * 16 + lm;
      const bf16x8 bb = *(const bf16x8*)&Bs[brow * 32 + ((lg ^ swz(brow)) << 3)];
      acc[0][ct] = __builtin_amdgcn_mfma_f32_16x16x32_bf16(af0, bb, acc[0][ct], 0, 0, 0);
      acc[1][ct] = __builtin_amdgcn_mfma_f32_16x16x32_bf16(af1, bb, acc[1][ct], 0, 0, 0);
    }
  }

  const bool isv = (bc >= 16);
  const int h = bc & 7;
#pragma unroll
  for (int rt = 0; rt < 2; ++rt) {
#pragma unroll
    for (int r = 0; r < 4; ++r) {
      const int t = row0 + w * 32 + rt * 16 + lg * 4 + r;
      const int slot = slots[t];
      if (!isv) {
        float ss = 0.f;
#pragma unroll
        for (int ct = 0; ct < 8; ++ct) ss = fmaf(acc[rt][ct][r], acc[rt][ct][r], ss);
        ss += __shfl_xor(ss, 1);
        ss += __shfl_xor(ss, 2);
        ss += __shfl_xor(ss, 4);
        ss += __shfl_xor(ss, 8);
        const float rs = rsqrtf(ss * (1.f / 128.f) + kEps);
#pragma unroll
        for (int ct = 0; ct < 8; ++ct) {
          const int col = ct * 16 + lm;
          const float x = acc[rt][ct][r] * rs;
          const float partner = __shfl_xor(x, 1);
          const float c = cosb[t * 64 + (col >> 1)];
          const float s = sinb[t * 64 + (col >> 1)];
          // even col: x*c - partner*s ; odd col: partner*s + x*c
          const float val = (lm & 1) ? fmaf(partner, s, x * c) : fmaf(-partner, s, x * c);
          if (bc < 8) {
            Qb[(size_t)t * kHid + h * kHS + col] = f2bf(val * kScale);
          } else {
            ock[(size_t)slot * kHid + h * kHS + col] = val;
            Kb[(size_t)t * kHid + h * kHS + col] = f2bf(val);
          }
        }
      } else {
#pragma unroll
        for (int ct = 0; ct < 8; ++ct) {
          const int col = ct * 16 + lm;
          const float val = acc[rt][ct][r];
          ocv[(size_t)slot * kHid + h * kHS + col] = val;
          Vb[(size_t)t * kHid + h * kHS + col] = f2bf(val);
        }
      }
    }
  }
}

// ---------------------------------------------------------------------------
// Flash attention, bf16 MFMA. Block = (64 q-rows, head); 4 waves, wave w owns
// q-strip w*16..+15. K-tile 64. Q/K in LDS row-major (+8 pad), V transposed in
// LDS (Vt[d][kt], +8 pad), P via f32 LDS. Diagonal tile masked only.
// ---------------------------------------------------------------------------
__global__ __launch_bounds__(256)
void attn_kernel(const short* __restrict__ Qb, const short* __restrict__ Kb,
                 const short* __restrict__ Vb, short* __restrict__ abuf) {
  __shared__ short Qs[64][136];
  __shared__ short Ks[64][136];
  __shared__ short Vt[128][72];
  __shared__ float Ps[64][68];

  const int qt = (int)gridDim.x - 1 - (int)blockIdx.x;  // long blocks first
  const int h = blockIdx.y;
  const int q0 = qt * 64;
  const int tid = threadIdx.x;
  const int lane = tid & 63, w = tid >> 6;
  const int lm = lane & 15, lg = lane >> 4;
  const int qw0 = w * 16;

  // Stage Q (64x128 bf16, already normed/roped/scaled).
  {
    const int r = tid >> 2, c0 = (tid & 3) * 32;
    const bf16x8* src = (const bf16x8*)&Qb[(size_t)(q0 + r) * kHid + h * kHS + c0];
    bf16x8* dst = (bf16x8*)&Qs[r][c0];
    dst[0] = src[0]; dst[1] = src[1]; dst[2] = src[2]; dst[3] = src[3];
  }

  float m[4], l[4];
  f32x4 o[8];
#pragma unroll
  for (int r = 0; r < 4; ++r) { m[r] = kNeg; l[r] = 0.f; }
#pragma unroll
  for (int dt = 0; dt < 8; ++dt) o[dt] = (f32x4){0.f, 0.f, 0.f, 0.f};

  for (int j0 = 0; j0 <= q0; j0 += 64) {
    __syncthreads();  // prior tile's K/Vt reads complete (also covers Q stage)
    {  // stage K tile
      const int r = tid >> 2, c0 = (tid & 3) * 32;
      const bf16x8* src = (const bf16x8*)&Kb[(size_t)(j0 + r) * kHid + h * kHS + c0];
      bf16x8* dst = (bf16x8*)&Ks[r][c0];
      dst[0] = src[0]; dst[1] = src[1]; dst[2] = src[2]; dst[3] = src[3];
    }
    {  // stage V transposed: Vt[d][kt]
      const int kt = (tid & 31) * 2;
      const int dbase = (tid >> 5) * 4;
#pragma unroll
      for (int pass = 0; pass < 4; ++pass) {
        const int d0 = dbase + pass * 32;
        const ushort4 va = *(const ushort4*)&Vb[(size_t)(j0 + kt) * kHid + h * kHS + d0];
        const ushort4 vb2 = *(const ushort4*)&Vb[(size_t)(j0 + kt + 1) * kHid + h * kHS + d0];
        *(unsigned*)&Vt[d0 + 0][kt] = (unsigned)va.x | ((unsigned)vb2.x << 16);
        *(unsigned*)&Vt[d0 + 1][kt] = (unsigned)va.y | ((unsigned)vb2.y << 16);
        *(unsigned*)&Vt[d0 + 2][kt] = (unsigned)va.z | ((unsigned)vb2.z << 16);
        *(unsigned*)&Vt[d0 + 3][kt] = (unsigned)va.w | ((unsigned)vb2.w << 16);
      }
    }
    __syncthreads();

    // S = Q K^T : wave's 16 q-rows x 64 keys (4 col-tiles).
    f32x4 s[4];
#pragma unroll
    for (int kb = 0; kb < 4; ++kb) s[kb] = (f32x4){0.f, 0.f, 0.f, 0.f};
#pragma unroll
    for (int dc = 0; dc < 4; ++dc) {
      const bf16x8 a = *(const bf16x8*)&Qs[qw0 + lm][dc * 32 + lg * 8];
#pragma unroll
      for (int kb = 0; kb < 4; ++kb) {
        const bf16x8 b = *(const bf16x8*)&Ks[kb * 16 + lm][dc * 32 + lg * 8];
        s[kb] = __builtin_amdgcn_mfma_f32_16x16x32_bf16(a, b, s[kb], 0, 0, 0);
      }
    }

    // Online softmax. Lane owns rows lg*4+r (within strip), col lm per tile.
    const bool diag = (j0 == q0);
#pragma unroll
    for (int r = 0; r < 4; ++r) {
      const int qrow = q0 + qw0 + lg * 4 + r;
      float sv[4];
#pragma unroll
      for (int kb = 0; kb < 4; ++kb) {
        sv[kb] = s[kb][r];
        if (diag && (j0 + kb * 16 + lm) > qrow) sv[kb] = kNeg;
      }
      float mx = fmaxf(fmaxf(sv[0], sv[1]), fmaxf(sv[2], sv[3]));
      mx = fmaxf(mx, __shfl_xor(mx, 1));
      mx = fmaxf(mx, __shfl_xor(mx, 2));
      mx = fmaxf(mx, __shfl_xor(mx, 4));
      mx = fmaxf(mx, __shfl_xor(mx, 8));
      const float mnew = fmaxf(m[r], mx);
      const float alpha = __expf(m[r] - mnew);
      float ps = 0.f;
#pragma unroll
      for (int kb = 0; kb < 4; ++kb) {
        const float p = __expf(sv[kb] - mnew);
        ps += p;
        Ps[qw0 + lg * 4 + r][kb * 16 + lm] = p;
      }
      ps += __shfl_xor(ps, 1);
      ps += __shfl_xor(ps, 2);
      ps += __shfl_xor(ps, 4);
      ps += __shfl_xor(ps, 8);
      l[r] = l[r] * alpha + ps;
      m[r] = mnew;
#pragma unroll
      for (int dt = 0; dt < 8; ++dt) o[dt][r] *= alpha;
    }
    // No barrier: PV reads only this wave's Ps rows; Vt synced above.

    // O += P V.
#pragma unroll
    for (int kc = 0; kc < 2; ++kc) {
      const float4 p0 = *(const float4*)&Ps[qw0 + lm][kc * 32 + lg * 8];
      const float4 p1 = *(const float4*)&Ps[qw0 + lm][kc * 32 + lg * 8 + 4];
      const bf16x8 pa = pack_bf8(p0, p1);
#pragma unroll
      for (int dt = 0; dt < 8; ++dt) {
        const bf16x8 b = *(const bf16x8*)&Vt[dt * 16 + lm][kc * 32 + lg * 8];
        o[dt] = __builtin_amdgcn_mfma_f32_16x16x32_bf16(pa, b, o[dt], 0, 0, 0);
      }
    }
  }

#pragma unroll
  for (int r = 0; r < 4; ++r) {
    const float inv = 1.f / l[r];
    const int t = q0 + qw0 + lg * 4 + r;
#pragma unroll
    for (int dt = 0; dt < 8; ++dt)
      abuf[(size_t)t * kHid + h * kHS + dt * 16 + lm] = f2bf(o[dt][r] * inv);
  }
}

// ---------------------------------------------------------------------------
// Output GEMM (bf16 MFMA): out = attn(bf16) @ Wo^T. Same tiling as qkv.
// ---------------------------------------------------------------------------
__global__ __launch_bounds__(256)
void out_gemm_kernel(const short* __restrict__ A, const float* __restrict__ W,
                     float* __restrict__ C) {
  __shared__ short As[128 * 32];
  __shared__ short Bs[128 * 32];
  const int row0 = blockIdx.x * 128;
  const int col0 = blockIdx.y * 128;
  const int tid = threadIdx.x;
  const int lane = tid & 63, w = tid >> 6;
  const int lm = lane & 15, lg = lane >> 4;
  const int r_st = tid >> 1, k_st = (tid & 1) * 16;

  f32x4 acc[2][8];
#pragma unroll
  for (int rt = 0; rt < 2; ++rt)
#pragma unroll
    for (int ct = 0; ct < 8; ++ct) acc[rt][ct] = (f32x4){0.f, 0.f, 0.f, 0.f};

  const short* ap = A + (size_t)(row0 + r_st) * kHid + k_st;
  const float* bp = W + (size_t)(col0 + r_st) * kHid + k_st;
  const int arow0 = w * 32 + lm, arow1 = w * 32 + 16 + lm;

  for (int k0 = 0; k0 < kHid; k0 += 32) {
    const bf16x8 a0 = *(const bf16x8*)(ap + k0);
    const bf16x8 a1 = *(const bf16x8*)(ap + k0 + 8);
    const float4 b0 = *(const float4*)(bp + k0);
    const float4 b1 = *(const float4*)(bp + k0 + 4);
    const float4 b2 = *(const float4*)(bp + k0 + 8);
    const float4 b3 = *(const float4*)(bp + k0 + 12);
    __syncthreads();
    {
      const int sw = swz(r_st);
      const int s0 = k_st >> 3;
      *(bf16x8*)&As[r_st * 32 + (((s0 + 0) ^ sw) << 3)] = a0;
      *(bf16x8*)&As[r_st * 32 + (((s0 + 1) ^ sw) << 3)] = a1;
    }
    stage16(Bs, r_st, k_st, b0, b1, b2, b3);
    __syncthreads();
    const bf16x8 af0 = *(const bf16x8*)&As[arow0 * 32 + ((lg ^ swz(arow0)) << 3)];
    const bf16x8 af1 = *(const bf16x8*)&As[arow1 * 32 + ((lg ^ swz(arow1)) << 3)];
#pragma unroll
    for (int ct = 0; ct < 8; ++ct) {
      const int brow = ct * 16 + lm;
      const bf16x8 bb = *(const bf16x8*)&Bs[brow * 32 + ((lg ^ swz(brow)) << 3)];
      acc[0][ct] = __builtin_amdgcn_mfma_f32_16x16x32_bf16(af0, bb, acc[0][ct], 0, 0, 0);
      acc[1][ct] = __builtin_amdgcn_mfma_f32_16x16x32_bf16(af1, bb, acc[1][ct], 0, 0, 0);
    }
  }

#pragma unroll
  for (int rt = 0; rt < 2; ++rt)
#pragma unroll
    for (int r = 0; r < 4; ++r) {
      const int row = row0 + w * 32 + rt * 16 + lg * 4 + r;
#pragma unroll
      for (int ct = 0; ct < 8; ++ct)
        C[(size_t)row * kHid + col0 + ct * 16 + lm] = acc[rt][ct][r];
    }
}

}  // namespace

extern "C" void kernel_launch(void* const* d_in, const int* in_sizes, int n_in,
                              void* d_out, int out_size, void* d_ws, size_t ws_size,
                              hipStream_t stream) {
  (void)in_sizes; (void)n_in; (void)out_size; (void)ws_size;
  const float* H = (const float*)d_in[0];
  const float* cosb = (const float*)d_in[1];
  const float* sinb = (const float*)d_in[2];
  const float* Wqkv = (const float*)d_in[3];
  const float* Wo = (const float*)d_in[4];
  const int* slots = (const int*)d_in[5];
  const float* ck = (const float*)d_in[6];
  const float* cv = (const float*)d_in[7];

  float* out = (float*)d_out;
  float* ock = out + (size_t)kT * kHid;             // new_cache_k (f32)
  float* ocv = ock + (size_t)kNSlots * kNH * kHS;   // new_cache_v (f32)

  // bf16 operand buffers: Qb/Kb borrow the out region (16.78 MB, exact fit);
  // Vb + abuf live in ws (16.78 MB, proven available).
  short* Qb = (short*)out;
  short* Kb = Qb + (size_t)kT * kHid;
  short* Vb = (short*)d_ws;
  short* abuf = Vb + (size_t)kT * kHid;

  const size_t cache_bytes = (size_t)kNSlots * kNH * kHS * sizeof(float);
  hipMemcpyAsync(ock, ck, cache_bytes, hipMemcpyDeviceToDevice, stream);
  hipMemcpyAsync(ocv, cv, cache_bytes, hipMemcpyDeviceToDevice, stream);

  qkv_gemm_kernel<<<dim3(kT / 128, 24), 256, 0, stream>>>(
      H, Wqkv, cosb, sinb, slots, Qb, Kb, Vb, ock, ocv);
  attn_kernel<<<dim3(kT / 64, kNH), 256, 0, stream>>>(Qb, Kb, Vb, abuf);
  out_gemm_kernel<<<dim3(kT / 128, kHid / 128), 256, 0, stream>>>(abuf, Wo, out);
}

// Round 3
// 337.326 us; speedup vs baseline: 5.9546x; 1.0153x over previous
//
#include <hip/hip_runtime.h>
#include <hip/hip_bf16.h>

namespace {

constexpr int kT = 4096;
constexpr int kHid = 1024;
constexpr int kNH = 8;
constexpr int kHS = 128;
constexpr int kNSlots = 8192;
constexpr float kEps = 1e-6f;
constexpr float kScale = 0.08838834764831845f;  // 128^-0.5
constexpr float kNeg = -1e30f;

typedef __attribute__((ext_vector_type(8))) short bf16x8;
typedef __attribute__((ext_vector_type(4))) float f32x4;

__device__ __forceinline__ short f2bf(float x) {
  unsigned u = __builtin_bit_cast(unsigned, x);
  unsigned r = (u + 0x7FFFu + ((u >> 16) & 1u)) >> 16;
  return (short)r;
}

__device__ __forceinline__ bf16x8 pack_bf8(float4 a, float4 b) {
  bf16x8 r;
  r[0] = f2bf(a.x); r[1] = f2bf(a.y); r[2] = f2bf(a.z); r[3] = f2bf(a.w);
  r[4] = f2bf(b.x); r[5] = f2bf(b.y); r[6] = f2bf(b.z); r[7] = f2bf(b.w);
  return r;
}

// 16B-slot XOR swizzle for [row][32 bf16] LDS tiles (64B rows) in the GEMMs.
__device__ __forceinline__ int swz(int r) { return ((r >> 1) ^ (r >> 3)) & 3; }

__device__ __forceinline__ void stage16(short* tile, int r, int k0,
                                        float4 a, float4 b, float4 c, float4 d) {
  const int sw = swz(r);
  const int s0 = k0 >> 3;  // 0 or 2
  *(bf16x8*)&tile[r * 32 + (((s0 + 0) ^ sw) << 3)] = pack_bf8(a, b);
  *(bf16x8*)&tile[r * 32 + (((s0 + 1) ^ sw) << 3)] = pack_bf8(c, d);
}

// Attention LDS address helpers: guide G4 swizzle, byte ^= ((row&7)<<4).
__device__ __forceinline__ short* kptr(short* base, int r, int c) {
  return (short*)((char*)base + ((r * 256 + c * 2) ^ ((r & 7) << 4)));
}
__device__ __forceinline__ const short* kptr(const short* base, int r, int c) {
  return (const short*)((const char*)base + ((r * 256 + c * 2) ^ ((r & 7) << 4)));
}
__device__ __forceinline__ short* vptr(short* base, int d, int k) {
  return (short*)((char*)base + ((d * 128 + k * 2) ^ ((d & 7) << 4)));
}
__device__ __forceinline__ float* pptr(float* base, int r, int c) {
  return (float*)((char*)base + ((r * 256 + c * 4) ^ ((r & 7) << 4)));
}

// ---------------------------------------------------------------------------
// QKV GEMM (bf16 MFMA): unchanged from round 2 (passing).
// ---------------------------------------------------------------------------
__global__ __launch_bounds__(256)
void qkv_gemm_kernel(const float* __restrict__ H, const float* __restrict__ W,
                     const float* __restrict__ cosb, const float* __restrict__ sinb,
                     const int* __restrict__ slots,
                     short* __restrict__ Qb, short* __restrict__ Kb,
                     short* __restrict__ Vb,
                     float* __restrict__ ock, float* __restrict__ ocv) {
  __shared__ short As[128 * 32];
  __shared__ short Bs[128 * 32];
  const int row0 = blockIdx.x * 128;
  const int bc = blockIdx.y;            // 0..7 q, 8..15 k, 16..23 v
  const int col0 = bc * 128;
  const int tid = threadIdx.x;
  const int lane = tid & 63, w = tid >> 6;
  const int lm = lane & 15, lg = lane >> 4;
  const int r_st = tid >> 1, k_st = (tid & 1) * 16;

  f32x4 acc[2][8];
#pragma unroll
  for (int rt = 0; rt < 2; ++rt)
#pragma unroll
    for (int ct = 0; ct < 8; ++ct) acc[rt][ct] = (f32x4){0.f, 0.f, 0.f, 0.f};

  const float* ap = H + (size_t)(row0 + r_st) * kHid + k_st;
  const float* bp = W + (size_t)(col0 + r_st) * kHid + k_st;
  const int arow0 = w * 32 + lm, arow1 = w * 32 + 16 + lm;

  for (int k0 = 0; k0 < kHid; k0 += 32) {
    const float4 a0 = *(const float4*)(ap + k0);
    const float4 a1 = *(const float4*)(ap + k0 + 4);
    const float4 a2 = *(const float4*)(ap + k0 + 8);
    const float4 a3 = *(const float4*)(ap + k0 + 12);
    const float4 b0 = *(const float4*)(bp + k0);
    const float4 b1 = *(const float4*)(bp + k0 + 4);
    const float4 b2 = *(const float4*)(bp + k0 + 8);
    const float4 b3 = *(const float4*)(bp + k0 + 12);
    __syncthreads();
    stage16(As, r_st, k_st, a0, a1, a2, a3);
    stage16(Bs, r_st, k_st, b0, b1, b2, b3);
    __syncthreads();
    const bf16x8 af0 = *(const bf16x8*)&As[arow0 * 32 + ((lg ^ swz(arow0)) << 3)];
    const bf16x8 af1 = *(const bf16x8*)&As[arow1 * 32 + ((lg ^ swz(arow1)) << 3)];
#pragma unroll
    for (int ct = 0; ct < 8; ++ct) {
      const int brow = ct * 16 + lm;
      const bf16x8 bb = *(const bf16x8*)&Bs[brow * 32 + ((lg ^ swz(brow)) << 3)];
      acc[0][ct] = __builtin_amdgcn_mfma_f32_16x16x32_bf16(af0, bb, acc[0][ct], 0, 0, 0);
      acc[1][ct] = __builtin_amdgcn_mfma_f32_16x16x32_bf16(af1, bb, acc[1][ct], 0, 0, 0);
    }
  }

  const bool isv = (bc >= 16);
  const int h = bc & 7;
#pragma unroll
  for (int rt = 0; rt < 2; ++rt) {
#pragma unroll
    for (int r = 0; r < 4; ++r) {
      const int t = row0 + w * 32 + rt * 16 + lg * 4 + r;
      const int slot = slots[t];
      if (!isv) {
        float ss = 0.f;
#pragma unroll
        for (int ct = 0; ct < 8; ++ct) ss = fmaf(acc[rt][ct][r], acc[rt][ct][r], ss);
        ss += __shfl_xor(ss, 1);
        ss += __shfl_xor(ss, 2);
        ss += __shfl_xor(ss, 4);
        ss += __shfl_xor(ss, 8);
        const float rs = rsqrtf(ss * (1.f / 128.f) + kEps);
#pragma unroll
        for (int ct = 0; ct < 8; ++ct) {
          const int col = ct * 16 + lm;
          const float x = acc[rt][ct][r] * rs;
          const float partner = __shfl_xor(x, 1);
          const float c = cosb[t * 64 + (col >> 1)];
          const float s = sinb[t * 64 + (col >> 1)];
          const float val = (lm & 1) ? fmaf(partner, s, x * c) : fmaf(-partner, s, x * c);
          if (bc < 8) {
            Qb[(size_t)t * kHid + h * kHS + col] = f2bf(val * kScale);
          } else {
            ock[(size_t)slot * kHid + h * kHS + col] = val;
            Kb[(size_t)t * kHid + h * kHS + col] = f2bf(val);
          }
        }
      } else {
#pragma unroll
        for (int ct = 0; ct < 8; ++ct) {
          const int col = ct * 16 + lm;
          const float val = acc[rt][ct][r];
          ocv[(size_t)slot * kHid + h * kHS + col] = val;
          Vb[(size_t)t * kHid + h * kHS + col] = f2bf(val);
        }
      }
    }
  }
}

// ---------------------------------------------------------------------------
// Flash attention v3: Q in registers, XOR-swizzled LDS (Ks/Vt/Ps),
// async-STAGE split (prefetch next tile into regs before compute),
// XCD head-locality + causal pairing, setprio around MFMA.
// Block = 64 q-rows x head; 4 waves, wave w owns q-strip w*16..+15.
// ---------------------------------------------------------------------------
__global__ __launch_bounds__(256, 2)
void attn_kernel(const short* __restrict__ Qb, const short* __restrict__ Kb,
                 const short* __restrict__ Vb, short* __restrict__ abuf) {
  __shared__ short Ks[64 * 128];   // [key][d], swizzled
  __shared__ short Vt[128 * 64];   // [d][key], swizzled
  __shared__ float Ps[64 * 64];    // [q][key], swizzled

  const int flat = blockIdx.x;
  const int h = flat & 7;                    // XCD round-robin -> head/XCD
  const int i = flat >> 3;                   // 0..63
  const int qt = (i < 32) ? (63 - i) : (i - 32);  // pair long+short per CU
  const int q0 = qt * 64;
  const int tid = threadIdx.x;
  const int lane = tid & 63, w = tid >> 6;
  const int lm = lane & 15, lg = lane >> 4;
  const int qw0 = w * 16;

  // Q fragments straight to registers (scaled/normed/roped already).
  bf16x8 qf[4];
  {
    const short* qp = Qb + (size_t)(q0 + qw0 + lm) * kHid + h * kHS + lg * 8;
    qf[0] = *(const bf16x8*)(qp);
    qf[1] = *(const bf16x8*)(qp + 32);
    qf[2] = *(const bf16x8*)(qp + 64);
    qf[3] = *(const bf16x8*)(qp + 96);
  }

  // Staging assignments.
  const int kr = tid >> 2, kc0 = (tid & 3) * 32;        // K: row kr, cols kc0..+31
  const int vk = (tid & 31) * 2, vd0 = (tid >> 5) * 4;  // V: key pair vk, d-base vd0

  bf16x8 kreg[4];
  ushort4 va[4], vb[4];

  // Prologue: load + stage tile 0.
  {
    const short* kp = Kb + (size_t)kr * kHid + h * kHS + kc0;
#pragma unroll
    for (int s = 0; s < 4; ++s) kreg[s] = *(const bf16x8*)(kp + s * 8);
#pragma unroll
    for (int p = 0; p < 4; ++p) {
      const int d0 = vd0 + p * 32;
      va[p] = *(const ushort4*)&Vb[(size_t)vk * kHid + h * kHS + d0];
      vb[p] = *(const ushort4*)&Vb[(size_t)(vk + 1) * kHid + h * kHS + d0];
    }
#pragma unroll
    for (int s = 0; s < 4; ++s) *(bf16x8*)kptr(Ks, kr, kc0 + s * 8) = kreg[s];
#pragma unroll
    for (int p = 0; p < 4; ++p) {
      const int d0 = vd0 + p * 32;
      const unsigned lo[4] = {va[p].x, va[p].y, va[p].z, va[p].w};
      const unsigned hi[4] = {vb[p].x, vb[p].y, vb[p].z, vb[p].w};
#pragma unroll
      for (int ii = 0; ii < 4; ++ii)
        *(unsigned*)vptr(Vt, d0 + ii, vk) = lo[ii] | (hi[ii] << 16);
    }
  }
  __syncthreads();

  float m[4], l[4];
  f32x4 o[8];
#pragma unroll
  for (int r = 0; r < 4; ++r) { m[r] = kNeg; l[r] = 0.f; }
#pragma unroll
  for (int dt = 0; dt < 8; ++dt) o[dt] = (f32x4){0.f, 0.f, 0.f, 0.f};

  int j0 = 0;
  for (;;) {
    const int jn = j0 + 64;
    const bool more = (jn <= q0);
    if (more) {  // T14: issue next tile's loads before compute
      const short* kp = Kb + (size_t)(jn + kr) * kHid + h * kHS + kc0;
#pragma unroll
      for (int s = 0; s < 4; ++s) kreg[s] = *(const bf16x8*)(kp + s * 8);
#pragma unroll
      for (int p = 0; p < 4; ++p) {
        const int d0 = vd0 + p * 32;
        va[p] = *(const ushort4*)&Vb[(size_t)(jn + vk) * kHid + h * kHS + d0];
        vb[p] = *(const ushort4*)&Vb[(size_t)(jn + vk + 1) * kHid + h * kHS + d0];
      }
    }

    // S = Q K^T.
    f32x4 s[4];
#pragma unroll
    for (int kb = 0; kb < 4; ++kb) s[kb] = (f32x4){0.f, 0.f, 0.f, 0.f};
    __builtin_amdgcn_s_setprio(1);
#pragma unroll
    for (int dc = 0; dc < 4; ++dc) {
#pragma unroll
      for (int kb = 0; kb < 4; ++kb) {
        const bf16x8 b = *(const bf16x8*)kptr(Ks, kb * 16 + lm, dc * 32 + lg * 8);
        s[kb] = __builtin_amdgcn_mfma_f32_16x16x32_bf16(qf[dc], b, s[kb], 0, 0, 0);
      }
    }
    __builtin_amdgcn_s_setprio(0);

    // Online softmax (lane: rows lg*4+r of the strip, col lm per 16-tile).
    const bool diag = (j0 == q0);
#pragma unroll
    for (int r = 0; r < 4; ++r) {
      const int qrow = q0 + qw0 + lg * 4 + r;
      float sv[4];
#pragma unroll
      for (int kb = 0; kb < 4; ++kb) {
        sv[kb] = s[kb][r];
        if (diag && (j0 + kb * 16 + lm) > qrow) sv[kb] = kNeg;
      }
      float mx = fmaxf(fmaxf(sv[0], sv[1]), fmaxf(sv[2], sv[3]));
      mx = fmaxf(mx, __shfl_xor(mx, 1));
      mx = fmaxf(mx, __shfl_xor(mx, 2));
      mx = fmaxf(mx, __shfl_xor(mx, 4));
      mx = fmaxf(mx, __shfl_xor(mx, 8));
      const float mnew = fmaxf(m[r], mx);
      const float alpha = __expf(m[r] - mnew);
      float ps = 0.f;
#pragma unroll
      for (int kb = 0; kb < 4; ++kb) {
        const float p = __expf(sv[kb] - mnew);
        ps += p;
        *pptr(Ps, qw0 + lg * 4 + r, kb * 16 + lm) = p;
      }
      ps += __shfl_xor(ps, 1);
      ps += __shfl_xor(ps, 2);
      ps += __shfl_xor(ps, 4);
      ps += __shfl_xor(ps, 8);
      l[r] = l[r] * alpha + ps;
      m[r] = mnew;
#pragma unroll
      for (int dt = 0; dt < 8; ++dt) o[dt][r] *= alpha;
    }
    // No barrier: PV reads only this wave's Ps rows.

    // O += P V.
#pragma unroll
    for (int kc = 0; kc < 2; ++kc) {
      const float4 p0 = *(const float4*)pptr(Ps, qw0 + lm, kc * 32 + lg * 8);
      const float4 p1 = *(const float4*)pptr(Ps, qw0 + lm, kc * 32 + lg * 8 + 4);
      const bf16x8 pa = pack_bf8(p0, p1);
      __builtin_amdgcn_s_setprio(1);
#pragma unroll
      for (int dt = 0; dt < 8; ++dt) {
        const bf16x8 b = *(const bf16x8*)vptr(Vt, dt * 16 + lm, kc * 32 + lg * 8);
        o[dt] = __builtin_amdgcn_mfma_f32_16x16x32_bf16(pa, b, o[dt], 0, 0, 0);
      }
      __builtin_amdgcn_s_setprio(0);
    }

    if (!more) break;
    __syncthreads();  // all waves done reading Ks/Vt
#pragma unroll
    for (int s2 = 0; s2 < 4; ++s2) *(bf16x8*)kptr(Ks, kr, kc0 + s2 * 8) = kreg[s2];
#pragma unroll
    for (int p = 0; p < 4; ++p) {
      const int d0 = vd0 + p * 32;
      const unsigned lo[4] = {va[p].x, va[p].y, va[p].z, va[p].w};
      const unsigned hi[4] = {vb[p].x, vb[p].y, vb[p].z, vb[p].w};
#pragma unroll
      for (int ii = 0; ii < 4; ++ii)
        *(unsigned*)vptr(Vt, d0 + ii, vk) = lo[ii] | (hi[ii] << 16);
    }
    __syncthreads();
    j0 = jn;
  }

#pragma unroll
  for (int r = 0; r < 4; ++r) {
    const float inv = 1.f / l[r];
    const int t = q0 + qw0 + lg * 4 + r;
#pragma unroll
    for (int dt = 0; dt < 8; ++dt)
      abuf[(size_t)t * kHid + h * kHS + dt * 16 + lm] = f2bf(o[dt][r] * inv);
  }
}

// ---------------------------------------------------------------------------
// Output GEMM (bf16 MFMA): unchanged from round 2.
// ---------------------------------------------------------------------------
__global__ __launch_bounds__(256)
void out_gemm_kernel(const short* __restrict__ A, const float* __restrict__ W,
                     float* __restrict__ C) {
  __shared__ short As[128 * 32];
  __shared__ short Bs[128 * 32];
  const int row0 = blockIdx.x * 128;
  const int col0 = blockIdx.y * 128;
  const int tid = threadIdx.x;
  const int lane = tid & 63, w = tid >> 6;
  const int lm = lane & 15, lg = lane >> 4;
  const int r_st = tid >> 1, k_st = (tid & 1) * 16;

  f32x4 acc[2][8];
#pragma unroll
  for (int rt = 0; rt < 2; ++rt)
#pragma unroll
    for (int ct = 0; ct < 8; ++ct) acc[rt][ct] = (f32x4){0.f, 0.f, 0.f, 0.f};

  const short* ap = A + (size_t)(row0 + r_st) * kHid + k_st;
  const float* bp = W + (size_t)(col0 + r_st) * kHid + k_st;
  const int arow0 = w * 32 + lm, arow1 = w * 32 + 16 + lm;

  for (int k0 = 0; k0 < kHid; k0 += 32) {
    const bf16x8 a0 = *(const bf16x8*)(ap + k0);
    const bf16x8 a1 = *(const bf16x8*)(ap + k0 + 8);
    const float4 b0 = *(const float4*)(bp + k0);
    const float4 b1 = *(const float4*)(bp + k0 + 4);
    const float4 b2 = *(const float4*)(bp + k0 + 8);
    const float4 b3 = *(const float4*)(bp + k0 + 12);
    __syncthreads();
    {
      const int sw = swz(r_st);
      const int s0 = k_st >> 3;
      *(bf16x8*)&As[r_st * 32 + (((s0 + 0) ^ sw) << 3)] = a0;
      *(bf16x8*)&As[r_st * 32 + (((s0 + 1) ^ sw) << 3)] = a1;
    }
    stage16(Bs, r_st, k_st, b0, b1, b2, b3);
    __syncthreads();
    const bf16x8 af0 = *(const bf16x8*)&As[arow0 * 32 + ((lg ^ swz(arow0)) << 3)];
    const bf16x8 af1 = *(const bf16x8*)&As[arow1 * 32 + ((lg ^ swz(arow1)) << 3)];
#pragma unroll
    for (int ct = 0; ct < 8; ++ct) {
      const int brow = ct * 16 + lm;
      const bf16x8 bb = *(const bf16x8*)&Bs[brow * 32 + ((lg ^ swz(brow)) << 3)];
      acc[0][ct] = __builtin_amdgcn_mfma_f32_16x16x32_bf16(af0, bb, acc[0][ct], 0, 0, 0);
      acc[1][ct] = __builtin_amdgcn_mfma_f32_16x16x32_bf16(af1, bb, acc[1][ct], 0, 0, 0);
    }
  }

#pragma unroll
  for (int rt = 0; rt < 2; ++rt)
#pragma unroll
    for (int r = 0; r < 4; ++r) {
      const int row = row0 + w * 32 + rt * 16 + lg * 4 + r;
#pragma unroll
      for (int ct = 0; ct < 8; ++ct)
        C[(size_t)row * kHid + col0 + ct * 16 + lm] = acc[rt][ct][r];
    }
}

}  // namespace

extern "C" void kernel_launch(void* const* d_in, const int* in_sizes, int n_in,
                              void* d_out, int out_size, void* d_ws, size_t ws_size,
                              hipStream_t stream) {
  (void)in_sizes; (void)n_in; (void)out_size; (void)ws_size;
  const float* H = (const float*)d_in[0];
  const float* cosb = (const float*)d_in[1];
  const float* sinb = (const float*)d_in[2];
  const float* Wqkv = (const float*)d_in[3];
  const float* Wo = (const float*)d_in[4];
  const int* slots = (const int*)d_in[5];
  const float* ck = (const float*)d_in[6];
  const float* cv = (const float*)d_in[7];

  float* out = (float*)d_out;
  float* ock = out + (size_t)kT * kHid;             // new_cache_k (f32)
  float* ocv = ock + (size_t)kNSlots * kNH * kHS;   // new_cache_v (f32)

  short* Qb = (short*)out;       // borrow out region (dead until out_gemm)
  short* Kb = Qb + (size_t)kT * kHid;
  short* Vb = (short*)d_ws;
  short* abuf = Vb + (size_t)kT * kHid;

  const size_t cache_bytes = (size_t)kNSlots * kNH * kHS * sizeof(float);
  hipMemcpyAsync(ock, ck, cache_bytes, hipMemcpyDeviceToDevice, stream);
  hipMemcpyAsync(ocv, cv, cache_bytes, hipMemcpyDeviceToDevice, stream);

  qkv_gemm_kernel<<<dim3(kT / 128, 24), 256, 0, stream>>>(
      H, Wqkv, cosb, sinb, slots, Qb, Kb, Vb, ock, ocv);
  attn_kernel<<<512, 256, 0, stream>>>(Qb, Kb, Vb, abuf);
  out_gemm_kernel<<<dim3(kT / 128, kHid / 128), 256, 0, stream>>>(abuf, Wo, out);
}

// Round 4
// 241.478 us; speedup vs baseline: 8.3182x; 1.3969x over previous
//
#include <hip/hip_runtime.h>
#include <hip/hip_bf16.h>

namespace {

constexpr int kT = 4096;
constexpr int kHid = 1024;
constexpr int kNH = 8;
constexpr int kHS = 128;
constexpr int kNSlots = 8192;
constexpr float kEps = 1e-6f;
constexpr float kScale = 0.08838834764831845f;  // 128^-0.5
constexpr float kNeg = -1e30f;

typedef __attribute__((ext_vector_type(8))) short bf16x8;
typedef __attribute__((ext_vector_type(4))) float f32x4;
typedef __attribute__((ext_vector_type(16))) float f32x16;

__device__ __forceinline__ short f2bf(float x) {
  unsigned u = __builtin_bit_cast(unsigned, x);
  unsigned r = (u + 0x7FFFu + ((u >> 16) & 1u)) >> 16;
  return (short)r;
}

__device__ __forceinline__ bf16x8 pack_bf8(float4 a, float4 b) {
  bf16x8 r;
  r[0] = f2bf(a.x); r[1] = f2bf(a.y); r[2] = f2bf(a.z); r[3] = f2bf(a.w);
  r[4] = f2bf(b.x); r[5] = f2bf(b.y); r[6] = f2bf(b.z); r[7] = f2bf(b.w);
  return r;
}

__device__ __forceinline__ unsigned cvt_pk_bf16(float lo, float hi_) {
  unsigned r;
  asm("v_cvt_pk_bf16_f32 %0, %1, %2" : "=v"(r) : "v"(lo), "v"(hi_));
  return r;
}

__device__ __forceinline__ bf16x8 frag_from(unsigned w0, unsigned w1,
                                            unsigned w2, unsigned w3) {
  union { unsigned u[4]; bf16x8 v; } t;
  t.u[0] = w0; t.u[1] = w1; t.u[2] = w2; t.u[3] = w3;
  return t.v;
}

// 16B-slot XOR swizzle for [row][32 bf16] LDS tiles (64B rows) in the GEMMs.
__device__ __forceinline__ int swz(int r) { return ((r >> 1) ^ (r >> 3)) & 3; }

__device__ __forceinline__ void stage16(short* tile, int r, int k0,
                                        float4 a, float4 b, float4 c, float4 d) {
  const int sw = swz(r);
  const int s0 = k0 >> 3;  // 0 or 2
  *(bf16x8*)&tile[r * 32 + (((s0 + 0) ^ sw) << 3)] = pack_bf8(a, b);
  *(bf16x8*)&tile[r * 32 + (((s0 + 1) ^ sw) << 3)] = pack_bf8(c, d);
}

// Attention LDS address helpers: guide G4 swizzle, byte ^= ((row&7)<<4).
__device__ __forceinline__ short* kptr(short* base, int r, int c) {
  return (short*)((char*)base + ((r * 256 + c * 2) ^ ((r & 7) << 4)));
}
__device__ __forceinline__ const short* kptr(const short* base, int r, int c) {
  return (const short*)((const char*)base + ((r * 256 + c * 2) ^ ((r & 7) << 4)));
}
__device__ __forceinline__ short* vptr(short* base, int d, int k) {
  return (short*)((char*)base + ((d * 128 + k * 2) ^ ((d & 7) << 4)));
}
__device__ __forceinline__ const short* vptr(const short* base, int d, int k) {
  return (const short*)((const char*)base + ((d * 128 + k * 2) ^ ((d & 7) << 4)));
}

// ---------------------------------------------------------------------------
// QKV GEMM (bf16 MFMA): unchanged (passing).
// ---------------------------------------------------------------------------
__global__ __launch_bounds__(256)
void qkv_gemm_kernel(const float* __restrict__ H, const float* __restrict__ W,
                     const float* __restrict__ cosb, const float* __restrict__ sinb,
                     const int* __restrict__ slots,
                     short* __restrict__ Qb, short* __restrict__ Kb,
                     short* __restrict__ Vb,
                     float* __restrict__ ock, float* __restrict__ ocv) {
  __shared__ short As[128 * 32];
  __shared__ short Bs[128 * 32];
  const int row0 = blockIdx.x * 128;
  const int bc = blockIdx.y;            // 0..7 q, 8..15 k, 16..23 v
  const int col0 = bc * 128;
  const int tid = threadIdx.x;
  const int lane = tid & 63, w = tid >> 6;
  const int lm = lane & 15, lg = lane >> 4;
  const int r_st = tid >> 1, k_st = (tid & 1) * 16;

  f32x4 acc[2][8];
#pragma unroll
  for (int rt = 0; rt < 2; ++rt)
#pragma unroll
    for (int ct = 0; ct < 8; ++ct) acc[rt][ct] = (f32x4){0.f, 0.f, 0.f, 0.f};

  const float* ap = H + (size_t)(row0 + r_st) * kHid + k_st;
  const float* bp = W + (size_t)(col0 + r_st) * kHid + k_st;
  const int arow0 = w * 32 + lm, arow1 = w * 32 + 16 + lm;

  for (int k0 = 0; k0 < kHid; k0 += 32) {
    const float4 a0 = *(const float4*)(ap + k0);
    const float4 a1 = *(const float4*)(ap + k0 + 4);
    const float4 a2 = *(const float4*)(ap + k0 + 8);
    const float4 a3 = *(const float4*)(ap + k0 + 12);
    const float4 b0 = *(const float4*)(bp + k0);
    const float4 b1 = *(const float4*)(bp + k0 + 4);
    const float4 b2 = *(const float4*)(bp + k0 + 8);
    const float4 b3 = *(const float4*)(bp + k0 + 12);
    __syncthreads();
    stage16(As, r_st, k_st, a0, a1, a2, a3);
    stage16(Bs, r_st, k_st, b0, b1, b2, b3);
    __syncthreads();
    const bf16x8 af0 = *(const bf16x8*)&As[arow0 * 32 + ((lg ^ swz(arow0)) << 3)];
    const bf16x8 af1 = *(const bf16x8*)&As[arow1 * 32 + ((lg ^ swz(arow1)) << 3)];
#pragma unroll
    for (int ct = 0; ct < 8; ++ct) {
      const int brow = ct * 16 + lm;
      const bf16x8 bb = *(const bf16x8*)&Bs[brow * 32 + ((lg ^ swz(brow)) << 3)];
      acc[0][ct] = __builtin_amdgcn_mfma_f32_16x16x32_bf16(af0, bb, acc[0][ct], 0, 0, 0);
      acc[1][ct] = __builtin_amdgcn_mfma_f32_16x16x32_bf16(af1, bb, acc[1][ct], 0, 0, 0);
    }
  }

  const bool isv = (bc >= 16);
  const int h = bc & 7;
#pragma unroll
  for (int rt = 0; rt < 2; ++rt) {
#pragma unroll
    for (int r = 0; r < 4; ++r) {
      const int t = row0 + w * 32 + rt * 16 + lg * 4 + r;
      const int slot = slots[t];
      if (!isv) {
        float ss = 0.f;
#pragma unroll
        for (int ct = 0; ct < 8; ++ct) ss = fmaf(acc[rt][ct][r], acc[rt][ct][r], ss);
        ss += __shfl_xor(ss, 1);
        ss += __shfl_xor(ss, 2);
        ss += __shfl_xor(ss, 4);
        ss += __shfl_xor(ss, 8);
        const float rs = rsqrtf(ss * (1.f / 128.f) + kEps);
#pragma unroll
        for (int ct = 0; ct < 8; ++ct) {
          const int col = ct * 16 + lm;
          const float x = acc[rt][ct][r] * rs;
          const float partner = __shfl_xor(x, 1);
          const float c = cosb[t * 64 + (col >> 1)];
          const float s = sinb[t * 64 + (col >> 1)];
          const float val = (lm & 1) ? fmaf(partner, s, x * c) : fmaf(-partner, s, x * c);
          if (bc < 8) {
            Qb[(size_t)t * kHid + h * kHS + col] = f2bf(val * kScale);
          } else {
            ock[(size_t)slot * kHid + h * kHS + col] = val;
            Kb[(size_t)t * kHid + h * kHS + col] = f2bf(val);
          }
        }
      } else {
#pragma unroll
        for (int ct = 0; ct < 8; ++ct) {
          const int col = ct * 16 + lm;
          const float val = acc[rt][ct][r];
          ocv[(size_t)slot * kHid + h * kHS + col] = val;
          Vb[(size_t)t * kHid + h * kHS + col] = f2bf(val);
        }
      }
    }
  }
}

// ---------------------------------------------------------------------------
// Flash attention v4: 32x32x16 MFMA, swapped QK^T (S^T = K·Q) so softmax is
// in-register (q = lane&31); P->bf16 via v_cvt_pk + lane^32 exchange feeds
// PV's A-operand directly. Producer/consumer wave split: waves {2g} stage
// K/Vt into double-buffered LDS, waves {2g^1} compute. 1 barrier/step.
// Block = 64 q-rows x head; grid 512 (all resident), long/short pairing.
// ---------------------------------------------------------------------------
__global__ __launch_bounds__(256, 2)
void attn_kernel(const short* __restrict__ Qb, const short* __restrict__ Kb,
                 const short* __restrict__ Vb, short* __restrict__ abuf) {
  __shared__ short Ks[2][64 * 128];   // [buf][key][d], swizzled
  __shared__ short Vt[2][128 * 64];   // [buf][d][key], swizzled
  __shared__ float bcast[2][32];      // per-consumer-wave alpha / 1/l

  const int flat = blockIdx.x;
  const int h = flat & 7;                          // XCD round-robin -> head
  const int i = flat >> 3;
  const int qt = (i < 32) ? (63 - i) : (i - 32);   // long+short pairing
  const int q0 = qt * 64;
  const int nsteps = qt + 1;
  const int tid = threadIdx.x;
  const int w = tid >> 6;
  const int lane = tid & 63;
  const int lq = lane & 31, hi = lane >> 5;
  const int swap = (i >> 5) & 1;                   // spread MFMA waves on SIMDs
  const bool consumer = ((w >> 1) ^ swap) == 0;
  const int wc = w & 1;

  if (!consumer) {
    // -------- producer: stage K (row-major) + V (transposed), dbuf --------
    const int ptid = wc * 64 + lane;               // 0..127
    const int krow = ptid >> 1, kcol = (ptid & 1) * 64;
    const int vk = (ptid & 31) * 2, vd0 = (ptid >> 5) * 4;

    auto stage = [&](int j0, short* KsB, short* VtB) {
      const short* kp = Kb + (size_t)(j0 + krow) * kHid + h * kHS + kcol;
      bf16x8 kr[8];
#pragma unroll
      for (int u = 0; u < 8; ++u) kr[u] = *(const bf16x8*)(kp + u * 8);
      ushort4 va[8], vb4[8];
#pragma unroll
      for (int p = 0; p < 8; ++p) {
        const int d0 = vd0 + p * 16;
        va[p] = *(const ushort4*)&Vb[(size_t)(j0 + vk) * kHid + h * kHS + d0];
        vb4[p] = *(const ushort4*)&Vb[(size_t)(j0 + vk + 1) * kHid + h * kHS + d0];
      }
#pragma unroll
      for (int u = 0; u < 8; ++u) *(bf16x8*)kptr(KsB, krow, kcol + u * 8) = kr[u];
#pragma unroll
      for (int p = 0; p < 8; ++p) {
        const int d0 = vd0 + p * 16;
        const unsigned lo[4] = {va[p].x, va[p].y, va[p].z, va[p].w};
        const unsigned hh[4] = {vb4[p].x, vb4[p].y, vb4[p].z, vb4[p].w};
#pragma unroll
        for (int ii = 0; ii < 4; ++ii)
          *(unsigned*)vptr(VtB, d0 + ii, vk) = lo[ii] | (hh[ii] << 16);
      }
    };

    stage(0, Ks[0], Vt[0]);
    __syncthreads();
    for (int s = 0; s < nsteps; ++s) {
      if (s + 1 < nsteps) stage((s + 1) * 64, Ks[(s + 1) & 1], Vt[(s + 1) & 1]);
      __syncthreads();
    }
    return;
  }

  // -------------------------- consumer ---------------------------------
  const int qrow = q0 + wc * 32 + lq;              // this lane's q row

  // Q fragments (B-operand): 8 d-chunks, lane gives Q[q=lq][dc*16+hi*8 .. +7].
  bf16x8 qf[8];
  {
    const short* qp = Qb + (size_t)qrow * kHid + h * kHS + hi * 8;
#pragma unroll
    for (int dc = 0; dc < 8; ++dc) qf[dc] = *(const bf16x8*)(qp + dc * 16);
  }

  float m = kNeg, l = 0.f;
  f32x16 O[4];
#pragma unroll
  for (int dt = 0; dt < 4; ++dt)
#pragma unroll
    for (int r = 0; r < 16; ++r) O[dt][r] = 0.f;

  __syncthreads();  // buf0 staged

  for (int s = 0; s < nsteps; ++s) {
    const int j0 = s * 64;
    const short* KsB = Ks[s & 1];
    const short* VtB = Vt[s & 1];

    // ---- S^T = K · Q : st[kb] covers keys kb*32..+31 (rows) x 32 q (cols).
    f32x16 st[2];
#pragma unroll
    for (int kb = 0; kb < 2; ++kb)
#pragma unroll
      for (int r = 0; r < 16; ++r) st[kb][r] = 0.f;

    __builtin_amdgcn_s_setprio(1);
#pragma unroll
    for (int dc = 0; dc < 8; ++dc) {
#pragma unroll
      for (int kb = 0; kb < 2; ++kb) {
        const bf16x8 a = *(const bf16x8*)kptr(KsB, kb * 32 + lq, dc * 16 + hi * 8);
        st[kb] = __builtin_amdgcn_mfma_f32_32x32x16_bf16(a, qf[dc], st[kb], 0, 0, 0);
      }
    }
    __builtin_amdgcn_s_setprio(0);

    // ---- causal mask (diagonal tile only). key = j0+kb*32+(r&3)+8*(r>>2)+4*hi.
    if (j0 == q0) {
#pragma unroll
      for (int kb = 0; kb < 2; ++kb)
#pragma unroll
        for (int r = 0; r < 16; ++r) {
          const int ka = j0 + kb * 32 + (r & 3) + 8 * (r >> 2) + 4 * hi;
          if (ka > qrow) st[kb][r] = kNeg;
        }
    }

    // ---- online softmax, fully in-register (one q per lane).
    float tt[16];
#pragma unroll
    for (int r = 0; r < 16; ++r) tt[r] = fmaxf(st[0][r], st[1][r]);
#pragma unroll
    for (int d = 8; d >= 1; d >>= 1)
#pragma unroll
      for (int r = 0; r < d; ++r) tt[r] = fmaxf(tt[r], tt[r + d]);
    const float mx = fmaxf(tt[0], __shfl_xor(tt[0], 32));
    const float mnew = fmaxf(m, mx);
    const float alpha = __expf(m - mnew);
    m = mnew;

    float ts[16];
#pragma unroll
    for (int kb = 0; kb < 2; ++kb)
#pragma unroll
      for (int r = 0; r < 16; ++r) st[kb][r] = __expf(st[kb][r] - mnew);
#pragma unroll
    for (int r = 0; r < 16; ++r) ts[r] = st[0][r] + st[1][r];
#pragma unroll
    for (int d = 8; d >= 1; d >>= 1)
#pragma unroll
      for (int r = 0; r < d; ++r) ts[r] += ts[r + d];
    const float rsum = ts[0] + __shfl_xor(ts[0], 32);
    l = l * alpha + rsum;

    // ---- broadcast alpha to O-row layout; rescale O.
    if (!hi) bcast[wc][lq] = alpha;
    float4 av[4];
#pragma unroll
    for (int g = 0; g < 4; ++g) av[g] = *(const float4*)&bcast[wc][8 * g + 4 * hi];
#pragma unroll
    for (int dt = 0; dt < 4; ++dt)
#pragma unroll
      for (int r = 0; r < 16; ++r) O[dt][r] *= av[r >> 2][r & 3];

    // ---- P -> bf16 A-fragments via cvt_pk + lane^32 exchange (T12).
    bf16x8 pf[4];
#pragma unroll
    for (int kb = 0; kb < 2; ++kb) {
      unsigned wq[8];
#pragma unroll
      for (int u = 0; u < 8; ++u)
        wq[u] = cvt_pk_bf16(st[kb][2 * u], st[kb][2 * u + 1]);
      // chunk kc=2*kb (keys kb*32+0..15)
      {
        const unsigned z0 = hi ? wq[0] : wq[2];
        const unsigned z1 = hi ? wq[1] : wq[3];
        const unsigned s0 = __shfl_xor(z0, 32);
        const unsigned s1 = __shfl_xor(z1, 32);
        pf[2 * kb] = frag_from(hi ? s0 : wq[0], hi ? s1 : wq[1],
                               hi ? wq[2] : s0, hi ? wq[3] : s1);
      }
      // chunk kc=2*kb+1 (keys kb*32+16..31)
      {
        const unsigned z0 = hi ? wq[4] : wq[6];
        const unsigned z1 = hi ? wq[5] : wq[7];
        const unsigned s0 = __shfl_xor(z0, 32);
        const unsigned s1 = __shfl_xor(z1, 32);
        pf[2 * kb + 1] = frag_from(hi ? s0 : wq[4], hi ? s1 : wq[5],
                                   hi ? wq[6] : s0, hi ? wq[7] : s1);
      }
    }

    // ---- O += P · V.
    __builtin_amdgcn_s_setprio(1);
#pragma unroll
    for (int kc = 0; kc < 4; ++kc) {
#pragma unroll
      for (int dt = 0; dt < 4; ++dt) {
        const bf16x8 b = *(const bf16x8*)vptr(VtB, dt * 32 + lq, kc * 16 + hi * 8);
        O[dt] = __builtin_amdgcn_mfma_f32_32x32x16_bf16(pf[kc], b, O[dt], 0, 0, 0);
      }
    }
    __builtin_amdgcn_s_setprio(0);

    __syncthreads();  // next buf staged; this buf free
  }

  // ---- write out: O col = d = dt*32+lq, row = (r&3)+8*(r>>2)+4*hi.
  if (!hi) bcast[wc][lq] = 1.f / l;
  float4 iv[4];
#pragma unroll
  for (int g = 0; g < 4; ++g) iv[g] = *(const float4*)&bcast[wc][8 * g + 4 * hi];
#pragma unroll
  for (int dt = 0; dt < 4; ++dt)
#pragma unroll
    for (int r = 0; r < 16; ++r) {
      const int mrow = (r & 3) + 8 * (r >> 2) + 4 * hi;
      const int t = q0 + wc * 32 + mrow;
      abuf[(size_t)t * kHid + h * kHS + dt * 32 + lq] =
          f2bf(O[dt][r] * iv[r >> 2][r & 3]);
    }
}

// ---------------------------------------------------------------------------
// Output GEMM (bf16 MFMA): unchanged.
// ---------------------------------------------------------------------------
__global__ __launch_bounds__(256)
void out_gemm_kernel(const short* __restrict__ A, const float* __restrict__ W,
                     float* __restrict__ C) {
  __shared__ short As[128 * 32];
  __shared__ short Bs[128 * 32];
  const int row0 = blockIdx.x * 128;
  const int col0 = blockIdx.y * 128;
  const int tid = threadIdx.x;
  const int lane = tid & 63, w = tid >> 6;
  const int lm = lane & 15, lg = lane >> 4;
  const int r_st = tid >> 1, k_st = (tid & 1) * 16;

  f32x4 acc[2][8];
#pragma unroll
  for (int rt = 0; rt < 2; ++rt)
#pragma unroll
    for (int ct = 0; ct < 8; ++ct) acc[rt][ct] = (f32x4){0.f, 0.f, 0.f, 0.f};

  const short* ap = A + (size_t)(row0 + r_st) * kHid + k_st;
  const float* bp = W + (size_t)(col0 + r_st) * kHid + k_st;
  const int arow0 = w * 32 + lm, arow1 = w * 32 + 16 + lm;

  for (int k0 = 0; k0 < kHid; k0 += 32) {
    const bf16x8 a0 = *(const bf16x8*)(ap + k0);
    const bf16x8 a1 = *(const bf16x8*)(ap + k0 + 8);
    const float4 b0 = *(const float4*)(bp + k0);
    const float4 b1 = *(const float4*)(bp + k0 + 4);
    const float4 b2 = *(const float4*)(bp + k0 + 8);
    const float4 b3 = *(const float4*)(bp + k0 + 12);
    __syncthreads();
    {
      const int sw = swz(r_st);
      const int s0 = k_st >> 3;
      *(bf16x8*)&As[r_st * 32 + (((s0 + 0) ^ sw) << 3)] = a0;
      *(bf16x8*)&As[r_st * 32 + (((s0 + 1) ^ sw) << 3)] = a1;
    }
    stage16(Bs, r_st, k_st, b0, b1, b2, b3);
    __syncthreads();
    const bf16x8 af0 = *(const bf16x8*)&As[arow0 * 32 + ((lg ^ swz(arow0)) << 3)];
    const bf16x8 af1 = *(const bf16x8*)&As[arow1 * 32 + ((lg ^ swz(arow1)) << 3)];
#pragma unroll
    for (int ct = 0; ct < 8; ++ct) {
      const int brow = ct * 16 + lm;
      const bf16x8 bb = *(const bf16x8*)&Bs[brow * 32 + ((lg ^ swz(brow)) << 3)];
      acc[0][ct] = __builtin_amdgcn_mfma_f32_16x16x32_bf16(af0, bb, acc[0][ct], 0, 0, 0);
      acc[1][ct] = __builtin_amdgcn_mfma_f32_16x16x32_bf16(af1, bb, acc[1][ct], 0, 0, 0);
    }
  }

#pragma unroll
  for (int rt = 0; rt < 2; ++rt)
#pragma unroll
    for (int r = 0; r < 4; ++r) {
      const int row = row0 + w * 32 + rt * 16 + lg * 4 + r;
#pragma unroll
      for (int ct = 0; ct < 8; ++ct)
        C[(size_t)row * kHid + col0 + ct * 16 + lm] = acc[rt][ct][r];
    }
}

}  // namespace

extern "C" void kernel_launch(void* const* d_in, const int* in_sizes, int n_in,
                              void* d_out, int out_size, void* d_ws, size_t ws_size,
                              hipStream_t stream) {
  (void)in_sizes; (void)n_in; (void)out_size; (void)ws_size;
  const float* H = (const float*)d_in[0];
  const float* cosb = (const float*)d_in[1];
  const float* sinb = (const float*)d_in[2];
  const float* Wqkv = (const float*)d_in[3];
  const float* Wo = (const float*)d_in[4];
  const int* slots = (const int*)d_in[5];
  const float* ck = (const float*)d_in[6];
  const float* cv = (const float*)d_in[7];

  float* out = (float*)d_out;
  float* ock = out + (size_t)kT * kHid;             // new_cache_k (f32)
  float* ocv = ock + (size_t)kNSlots * kNH * kHS;   // new_cache_v (f32)

  short* Qb = (short*)out;       // borrow out region (dead until out_gemm)
  short* Kb = Qb + (size_t)kT * kHid;
  short* Vb = (short*)d_ws;
  short* abuf = Vb + (size_t)kT * kHid;

  const size_t cache_bytes = (size_t)kNSlots * kNH * kHS * sizeof(float);
  hipMemcpyAsync(ock, ck, cache_bytes, hipMemcpyDeviceToDevice, stream);
  hipMemcpyAsync(ocv, cv, cache_bytes, hipMemcpyDeviceToDevice, stream);

  qkv_gemm_kernel<<<dim3(kT / 128, 24), 256, 0, stream>>>(
      H, Wqkv, cosb, sinb, slots, Qb, Kb, Vb, ock, ocv);
  attn_kernel<<<512, 256, 0, stream>>>(Qb, Kb, Vb, abuf);
  out_gemm_kernel<<<dim3(kT / 128, kHid / 128), 256, 0, stream>>>(abuf, Wo, out);
}

// Round 5
// 240.519 us; speedup vs baseline: 8.3513x; 1.0040x over previous
//
#include <hip/hip_runtime.h>
#include <hip/hip_bf16.h>

namespace {

constexpr int kT = 4096;
constexpr int kHid = 1024;
constexpr int kNH = 8;
constexpr int kHS = 128;
constexpr int kNSlots = 8192;
constexpr float kEps = 1e-6f;
constexpr float kScale = 0.08838834764831845f;           // 128^-0.5
constexpr float kQScale = 0.12753102242f;                 // kScale * log2(e)
constexpr float kNeg = -1e30f;

typedef __attribute__((ext_vector_type(8))) short bf16x8;
typedef __attribute__((ext_vector_type(4))) float f32x4;
typedef __attribute__((ext_vector_type(16))) float f32x16;

__device__ __forceinline__ short f2bf(float x) {
  unsigned u = __builtin_bit_cast(unsigned, x);
  unsigned r = (u + 0x7FFFu + ((u >> 16) & 1u)) >> 16;
  return (short)r;
}

__device__ __forceinline__ bf16x8 pack_bf8(float4 a, float4 b) {
  bf16x8 r;
  r[0] = f2bf(a.x); r[1] = f2bf(a.y); r[2] = f2bf(a.z); r[3] = f2bf(a.w);
  r[4] = f2bf(b.x); r[5] = f2bf(b.y); r[6] = f2bf(b.z); r[7] = f2bf(b.w);
  return r;
}

__device__ __forceinline__ unsigned cvt_pk_bf16(float lo, float hi_) {
  unsigned r;
  asm("v_cvt_pk_bf16_f32 %0, %1, %2" : "=v"(r) : "v"(lo), "v"(hi_));
  return r;
}

__device__ __forceinline__ bf16x8 frag_from(unsigned w0, unsigned w1,
                                            unsigned w2, unsigned w3) {
  union { unsigned u[4]; bf16x8 v; } t;
  t.u[0] = w0; t.u[1] = w1; t.u[2] = w2; t.u[3] = w3;
  return t.v;
}

// 16B-slot XOR swizzle for [row][32 bf16] LDS tiles (64B rows) in the GEMMs.
__device__ __forceinline__ int swz(int r) { return ((r >> 1) ^ (r >> 3)) & 3; }

__device__ __forceinline__ void stage16(short* tile, int r, int k0,
                                        float4 a, float4 b, float4 c, float4 d) {
  const int sw = swz(r);
  const int s0 = k0 >> 3;  // 0 or 2
  *(bf16x8*)&tile[r * 32 + (((s0 + 0) ^ sw) << 3)] = pack_bf8(a, b);
  *(bf16x8*)&tile[r * 32 + (((s0 + 1) ^ sw) << 3)] = pack_bf8(c, d);
}

// Attention K tile: [64 key rows][128 d shorts] = 256B rows, 16-slot swizzle
// (rows read 32-at-a-time at one col slot -> need full 16-slot spread).
__device__ __forceinline__ short* kptr(short* base, int r, int c) {
  return (short*)((char*)base + ((r * 256 + c * 2) ^ ((r & 15) << 4)));
}
__device__ __forceinline__ const short* kptr(const short* base, int r, int c) {
  return (const short*)((const char*)base + ((r * 256 + c * 2) ^ ((r & 15) << 4)));
}
// Attention V tile, packed: V^T[d][k] at row=d>>1, col=(d&1)*64+k -> 256B rows.
__device__ __forceinline__ short* vptr2(short* base, int d, int k) {
  const int row = d >> 1;
  return (short*)((char*)base +
                  ((row * 256 + ((d & 1) * 64 + k) * 2) ^ ((row & 15) << 4)));
}
__device__ __forceinline__ const short* vptr2(const short* base, int d, int k) {
  const int row = d >> 1;
  return (const short*)((const char*)base +
                  ((row * 256 + ((d & 1) * 64 + k) * 2) ^ ((row & 15) << 4)));
}

// ---------------------------------------------------------------------------
// QKV GEMM (bf16 MFMA). Epilogue: l2norm + RoPE; Q pre-scaled by
// kScale*log2(e) (attention softmax runs in exp2 domain).
// ---------------------------------------------------------------------------
__global__ __launch_bounds__(256)
void qkv_gemm_kernel(const float* __restrict__ H, const float* __restrict__ W,
                     const float* __restrict__ cosb, const float* __restrict__ sinb,
                     const int* __restrict__ slots,
                     short* __restrict__ Qb, short* __restrict__ Kb,
                     short* __restrict__ Vb,
                     float* __restrict__ ock, float* __restrict__ ocv) {
  __shared__ short As[128 * 32];
  __shared__ short Bs[128 * 32];
  const int row0 = blockIdx.x * 128;
  const int bc = blockIdx.y;            // 0..7 q, 8..15 k, 16..23 v
  const int col0 = bc * 128;
  const int tid = threadIdx.x;
  const int lane = tid & 63, w = tid >> 6;
  const int lm = lane & 15, lg = lane >> 4;
  const int r_st = tid >> 1, k_st = (tid & 1) * 16;

  f32x4 acc[2][8];
#pragma unroll
  for (int rt = 0; rt < 2; ++rt)
#pragma unroll
    for (int ct = 0; ct < 8; ++ct) acc[rt][ct] = (f32x4){0.f, 0.f, 0.f, 0.f};

  const float* ap = H + (size_t)(row0 + r_st) * kHid + k_st;
  const float* bp = W + (size_t)(col0 + r_st) * kHid + k_st;
  const int arow0 = w * 32 + lm, arow1 = w * 32 + 16 + lm;

  for (int k0 = 0; k0 < kHid; k0 += 32) {
    const float4 a0 = *(const float4*)(ap + k0);
    const float4 a1 = *(const float4*)(ap + k0 + 4);
    const float4 a2 = *(const float4*)(ap + k0 + 8);
    const float4 a3 = *(const float4*)(ap + k0 + 12);
    const float4 b0 = *(const float4*)(bp + k0);
    const float4 b1 = *(const float4*)(bp + k0 + 4);
    const float4 b2 = *(const float4*)(bp + k0 + 8);
    const float4 b3 = *(const float4*)(bp + k0 + 12);
    __syncthreads();
    stage16(As, r_st, k_st, a0, a1, a2, a3);
    stage16(Bs, r_st, k_st, b0, b1, b2, b3);
    __syncthreads();
    const bf16x8 af0 = *(const bf16x8*)&As[arow0 * 32 + ((lg ^ swz(arow0)) << 3)];
    const bf16x8 af1 = *(const bf16x8*)&As[arow1 * 32 + ((lg ^ swz(arow1)) << 3)];
#pragma unroll
    for (int ct = 0; ct < 8; ++ct) {
      const int brow = ct * 16 + lm;
      const bf16x8 bb = *(const bf16x8*)&Bs[brow * 32 + ((lg ^ swz(brow)) << 3)];
      acc[0][ct] = __builtin_amdgcn_mfma_f32_16x16x32_bf16(af0, bb, acc[0][ct], 0, 0, 0);
      acc[1][ct] = __builtin_amdgcn_mfma_f32_16x16x32_bf16(af1, bb, acc[1][ct], 0, 0, 0);
    }
  }

  const bool isv = (bc >= 16);
  const int h = bc & 7;
#pragma unroll
  for (int rt = 0; rt < 2; ++rt) {
#pragma unroll
    for (int r = 0; r < 4; ++r) {
      const int t = row0 + w * 32 + rt * 16 + lg * 4 + r;
      const int slot = slots[t];
      if (!isv) {
        float ss = 0.f;
#pragma unroll
        for (int ct = 0; ct < 8; ++ct) ss = fmaf(acc[rt][ct][r], acc[rt][ct][r], ss);
        ss += __shfl_xor(ss, 1);
        ss += __shfl_xor(ss, 2);
        ss += __shfl_xor(ss, 4);
        ss += __shfl_xor(ss, 8);
        const float rs = rsqrtf(ss * (1.f / 128.f) + kEps);
#pragma unroll
        for (int ct = 0; ct < 8; ++ct) {
          const int col = ct * 16 + lm;
          const float x = acc[rt][ct][r] * rs;
          const float partner = __shfl_xor(x, 1);
          const float c = cosb[t * 64 + (col >> 1)];
          const float s = sinb[t * 64 + (col >> 1)];
          const float val = (lm & 1) ? fmaf(partner, s, x * c) : fmaf(-partner, s, x * c);
          if (bc < 8) {
            Qb[(size_t)t * kHid + h * kHS + col] = f2bf(val * kQScale);
          } else {
            ock[(size_t)slot * kHid + h * kHS + col] = val;
            Kb[(size_t)t * kHid + h * kHS + col] = f2bf(val);
          }
        }
      } else {
#pragma unroll
        for (int ct = 0; ct < 8; ++ct) {
          const int col = ct * 16 + lm;
          const float val = acc[rt][ct][r];
          ocv[(size_t)slot * kHid + h * kHS + col] = val;
          Vb[(size_t)t * kHid + h * kHS + col] = f2bf(val);
        }
      }
    }
  }
}

// ---------------------------------------------------------------------------
// Flash attention v5: v4 + (a) full 16-slot LDS swizzles (K rows 256B &15;
// V repacked 2-d-per-256B-row), (b) defer-max (T13, THR=8 in exp2 domain),
// (c) exp2-domain softmax (Q pre-scaled by log2e upstream).
// ---------------------------------------------------------------------------
__global__ __launch_bounds__(256, 2)
void attn_kernel(const short* __restrict__ Qb, const short* __restrict__ Kb,
                 const short* __restrict__ Vb, short* __restrict__ abuf) {
  __shared__ short Ks[2][64 * 128];   // [buf][key][d], swizzled, 256B rows
  __shared__ short Vp[2][64 * 128];   // [buf][d>>1][(d&1)*64+k], swizzled
  __shared__ float bcast[2][32];      // per-consumer-wave alpha / 1/l

  const int flat = blockIdx.x;
  const int h = flat & 7;                          // XCD round-robin -> head
  const int i = flat >> 3;
  const int qt = (i < 32) ? (63 - i) : (i - 32);   // long+short pairing
  const int q0 = qt * 64;
  const int nsteps = qt + 1;
  const int tid = threadIdx.x;
  const int w = tid >> 6;
  const int lane = tid & 63;
  const int lq = lane & 31, hi = lane >> 5;
  const int swap = (i >> 5) & 1;                   // spread MFMA waves on SIMDs
  const bool consumer = ((w >> 1) ^ swap) == 0;
  const int wc = w & 1;

  if (!consumer) {
    // -------- producer: stage K (row-major) + V (packed-T), dbuf --------
    const int ptid = wc * 64 + lane;               // 0..127
    const int krow = ptid >> 1, kcol = (ptid & 1) * 64;
    const int vk = (ptid & 31) * 2, vd0 = (ptid >> 5) * 4;

    auto stage = [&](int j0, short* KsB, short* VpB) {
      const short* kp = Kb + (size_t)(j0 + krow) * kHid + h * kHS + kcol;
      bf16x8 kr[8];
#pragma unroll
      for (int u = 0; u < 8; ++u) kr[u] = *(const bf16x8*)(kp + u * 8);
      ushort4 va[8], vb4[8];
#pragma unroll
      for (int p = 0; p < 8; ++p) {
        const int d0 = vd0 + p * 16;
        va[p] = *(const ushort4*)&Vb[(size_t)(j0 + vk) * kHid + h * kHS + d0];
        vb4[p] = *(const ushort4*)&Vb[(size_t)(j0 + vk + 1) * kHid + h * kHS + d0];
      }
#pragma unroll
      for (int u = 0; u < 8; ++u) *(bf16x8*)kptr(KsB, krow, kcol + u * 8) = kr[u];
#pragma unroll
      for (int p = 0; p < 8; ++p) {
        const int d0 = vd0 + p * 16;
        const unsigned lo[4] = {va[p].x, va[p].y, va[p].z, va[p].w};
        const unsigned hh[4] = {vb4[p].x, vb4[p].y, vb4[p].z, vb4[p].w};
#pragma unroll
        for (int ii = 0; ii < 4; ++ii)
          *(unsigned*)vptr2(VpB, d0 + ii, vk) = lo[ii] | (hh[ii] << 16);
      }
    };

    stage(0, Ks[0], Vp[0]);
    __syncthreads();
    for (int s = 0; s < nsteps; ++s) {
      if (s + 1 < nsteps) stage((s + 1) * 64, Ks[(s + 1) & 1], Vp[(s + 1) & 1]);
      __syncthreads();
    }
    return;
  }

  // -------------------------- consumer ---------------------------------
  const int qrow = q0 + wc * 32 + lq;              // this lane's q row

  // Q fragments (B-operand): lane gives Q[q=lq][dc*16+hi*8 .. +7].
  bf16x8 qf[8];
  {
    const short* qp = Qb + (size_t)qrow * kHid + h * kHS + hi * 8;
#pragma unroll
    for (int dc = 0; dc < 8; ++dc) qf[dc] = *(const bf16x8*)(qp + dc * 16);
  }

  float m = kNeg, l = 0.f;
  f32x16 O[4];
#pragma unroll
  for (int dt = 0; dt < 4; ++dt)
#pragma unroll
    for (int r = 0; r < 16; ++r) O[dt][r] = 0.f;

  __syncthreads();  // buf0 staged

  for (int s = 0; s < nsteps; ++s) {
    const int j0 = s * 64;
    const short* KsB = Ks[s & 1];
    const short* VpB = Vp[s & 1];

    // ---- S^T = K · Q (exp2-domain scores).
    f32x16 st[2];
#pragma unroll
    for (int kb = 0; kb < 2; ++kb)
#pragma unroll
      for (int r = 0; r < 16; ++r) st[kb][r] = 0.f;

    __builtin_amdgcn_s_setprio(1);
#pragma unroll
    for (int dc = 0; dc < 8; ++dc) {
#pragma unroll
      for (int kb = 0; kb < 2; ++kb) {
        const bf16x8 a = *(const bf16x8*)kptr(KsB, kb * 32 + lq, dc * 16 + hi * 8);
        st[kb] = __builtin_amdgcn_mfma_f32_32x32x16_bf16(a, qf[dc], st[kb], 0, 0, 0);
      }
    }
    __builtin_amdgcn_s_setprio(0);

    // ---- causal mask (diagonal tile only).
    if (j0 == q0) {
#pragma unroll
      for (int kb = 0; kb < 2; ++kb)
#pragma unroll
        for (int r = 0; r < 16; ++r) {
          const int ka = j0 + kb * 32 + (r & 3) + 8 * (r >> 2) + 4 * hi;
          if (ka > qrow) st[kb][r] = kNeg;
        }
    }

    // ---- online softmax with defer-max (T13).
    float tt[16];
#pragma unroll
    for (int r = 0; r < 16; ++r) tt[r] = fmaxf(st[0][r], st[1][r]);
#pragma unroll
    for (int d = 8; d >= 1; d >>= 1)
#pragma unroll
      for (int r = 0; r < d; ++r) tt[r] = fmaxf(tt[r], tt[r + d]);
    const float pmax = fmaxf(tt[0], __shfl_xor(tt[0], 32));

    if (!__all(pmax - m <= 8.f)) {
      const float mnew = fmaxf(m, pmax);
      const float alpha = exp2f(m - mnew);
      m = mnew;
      l *= alpha;
      if (!hi) bcast[wc][lq] = alpha;
      float4 av[4];
#pragma unroll
      for (int g = 0; g < 4; ++g) av[g] = *(const float4*)&bcast[wc][8 * g + 4 * hi];
#pragma unroll
      for (int dt = 0; dt < 4; ++dt)
#pragma unroll
        for (int r = 0; r < 16; ++r) O[dt][r] *= av[r >> 2][r & 3];
    }

    float ts[16];
#pragma unroll
    for (int kb = 0; kb < 2; ++kb)
#pragma unroll
      for (int r = 0; r < 16; ++r) st[kb][r] = exp2f(st[kb][r] - m);
#pragma unroll
    for (int r = 0; r < 16; ++r) ts[r] = st[0][r] + st[1][r];
#pragma unroll
    for (int d = 8; d >= 1; d >>= 1)
#pragma unroll
      for (int r = 0; r < d; ++r) ts[r] += ts[r + d];
    l += ts[0] + __shfl_xor(ts[0], 32);

    // ---- P -> bf16 A-fragments via cvt_pk + lane^32 exchange (T12).
    bf16x8 pf[4];
#pragma unroll
    for (int kb = 0; kb < 2; ++kb) {
      unsigned wq[8];
#pragma unroll
      for (int u = 0; u < 8; ++u)
        wq[u] = cvt_pk_bf16(st[kb][2 * u], st[kb][2 * u + 1]);
      {
        const unsigned z0 = hi ? wq[0] : wq[2];
        const unsigned z1 = hi ? wq[1] : wq[3];
        const unsigned s0 = __shfl_xor(z0, 32);
        const unsigned s1 = __shfl_xor(z1, 32);
        pf[2 * kb] = frag_from(hi ? s0 : wq[0], hi ? s1 : wq[1],
                               hi ? wq[2] : s0, hi ? wq[3] : s1);
      }
      {
        const unsigned z0 = hi ? wq[4] : wq[6];
        const unsigned z1 = hi ? wq[5] : wq[7];
        const unsigned s0 = __shfl_xor(z0, 32);
        const unsigned s1 = __shfl_xor(z1, 32);
        pf[2 * kb + 1] = frag_from(hi ? s0 : wq[4], hi ? s1 : wq[5],
                                   hi ? wq[6] : s0, hi ? wq[7] : s1);
      }
    }

    // ---- O += P · V.
    __builtin_amdgcn_s_setprio(1);
#pragma unroll
    for (int kc = 0; kc < 4; ++kc) {
#pragma unroll
      for (int dt = 0; dt < 4; ++dt) {
        const bf16x8 b = *(const bf16x8*)vptr2(VpB, dt * 32 + lq, kc * 16 + hi * 8);
        O[dt] = __builtin_amdgcn_mfma_f32_32x32x16_bf16(pf[kc], b, O[dt], 0, 0, 0);
      }
    }
    __builtin_amdgcn_s_setprio(0);

    __syncthreads();  // next buf staged; this buf free
  }

  // ---- write out: O col = d = dt*32+lq, row = (r&3)+8*(r>>2)+4*hi.
  if (!hi) bcast[wc][lq] = 1.f / l;
  float4 iv[4];
#pragma unroll
  for (int g = 0; g < 4; ++g) iv[g] = *(const float4*)&bcast[wc][8 * g + 4 * hi];
#pragma unroll
  for (int dt = 0; dt < 4; ++dt)
#pragma unroll
    for (int r = 0; r < 16; ++r) {
      const int mrow = (r & 3) + 8 * (r >> 2) + 4 * hi;
      const int t = q0 + wc * 32 + mrow;
      abuf[(size_t)t * kHid + h * kHS + dt * 32 + lq] =
          f2bf(O[dt][r] * iv[r >> 2][r & 3]);
    }
}

// ---------------------------------------------------------------------------
// Output GEMM (bf16 MFMA): unchanged.
// ---------------------------------------------------------------------------
__global__ __launch_bounds__(256)
void out_gemm_kernel(const short* __restrict__ A, const float* __restrict__ W,
                     float* __restrict__ C) {
  __shared__ short As[128 * 32];
  __shared__ short Bs[128 * 32];
  const int row0 = blockIdx.x * 128;
  const int col0 = blockIdx.y * 128;
  const int tid = threadIdx.x;
  const int lane = tid & 63, w = tid >> 6;
  const int lm = lane & 15, lg = lane >> 4;
  const int r_st = tid >> 1, k_st = (tid & 1) * 16;

  f32x4 acc[2][8];
#pragma unroll
  for (int rt = 0; rt < 2; ++rt)
#pragma unroll
    for (int ct = 0; ct < 8; ++ct) acc[rt][ct] = (f32x4){0.f, 0.f, 0.f, 0.f};

  const short* ap = A + (size_t)(row0 + r_st) * kHid + k_st;
  const float* bp = W + (size_t)(col0 + r_st) * kHid + k_st;
  const int arow0 = w * 32 + lm, arow1 = w * 32 + 16 + lm;

  for (int k0 = 0; k0 < kHid; k0 += 32) {
    const bf16x8 a0 = *(const bf16x8*)(ap + k0);
    const bf16x8 a1 = *(const bf16x8*)(ap + k0 + 8);
    const float4 b0 = *(const float4*)(bp + k0);
    const float4 b1 = *(const float4*)(bp + k0 + 4);
    const float4 b2 = *(const float4*)(bp + k0 + 8);
    const float4 b3 = *(const float4*)(bp + k0 + 12);
    __syncthreads();
    {
      const int sw = swz(r_st);
      const int s0 = k_st >> 3;
      *(bf16x8*)&As[r_st * 32 + (((s0 + 0) ^ sw) << 3)] = a0;
      *(bf16x8*)&As[r_st * 32 + (((s0 + 1) ^ sw) << 3)] = a1;
    }
    stage16(Bs, r_st, k_st, b0, b1, b2, b3);
    __syncthreads();
    const bf16x8 af0 = *(const bf16x8*)&As[arow0 * 32 + ((lg ^ swz(arow0)) << 3)];
    const bf16x8 af1 = *(const bf16x8*)&As[arow1 * 32 + ((lg ^ swz(arow1)) << 3)];
#pragma unroll
    for (int ct = 0; ct < 8; ++ct) {
      const int brow = ct * 16 + lm;
      const bf16x8 bb = *(const bf16x8*)&Bs[brow * 32 + ((lg ^ swz(brow)) << 3)];
      acc[0][ct] = __builtin_amdgcn_mfma_f32_16x16x32_bf16(af0, bb, acc[0][ct], 0, 0, 0);
      acc[1][ct] = __builtin_amdgcn_mfma_f32_16x16x32_bf16(af1, bb, acc[1][ct], 0, 0, 0);
    }
  }

#pragma unroll
  for (int rt = 0; rt < 2; ++rt)
#pragma unroll
    for (int r = 0; r < 4; ++r) {
      const int row = row0 + w * 32 + rt * 16 + lg * 4 + r;
#pragma unroll
      for (int ct = 0; ct < 8; ++ct)
        C[(size_t)row * kHid + col0 + ct * 16 + lm] = acc[rt][ct][r];
    }
}

}  // namespace

extern "C" void kernel_launch(void* const* d_in, const int* in_sizes, int n_in,
                              void* d_out, int out_size, void* d_ws, size_t ws_size,
                              hipStream_t stream) {
  (void)in_sizes; (void)n_in; (void)out_size; (void)ws_size;
  const float* H = (const float*)d_in[0];
  const float* cosb = (const float*)d_in[1];
  const float* sinb = (const float*)d_in[2];
  const float* Wqkv = (const float*)d_in[3];
  const float* Wo = (const float*)d_in[4];
  const int* slots = (const int*)d_in[5];
  const float* ck = (const float*)d_in[6];
  const float* cv = (const float*)d_in[7];

  float* out = (float*)d_out;
  float* ock = out + (size_t)kT * kHid;             // new_cache_k (f32)
  float* ocv = ock + (size_t)kNSlots * kNH * kHS;   // new_cache_v (f32)

  short* Qb = (short*)out;       // borrow out region (dead until out_gemm)
  short* Kb = Qb + (size_t)kT * kHid;
  short* Vb = (short*)d_ws;
  short* abuf = Vb + (size_t)kT * kHid;

  const size_t cache_bytes = (size_t)kNSlots * kNH * kHS * sizeof(float);
  hipMemcpyAsync(ock, ck, cache_bytes, hipMemcpyDeviceToDevice, stream);
  hipMemcpyAsync(ocv, cv, cache_bytes, hipMemcpyDeviceToDevice, stream);

  qkv_gemm_kernel<<<dim3(kT / 128, 24), 256, 0, stream>>>(
      H, Wqkv, cosb, sinb, slots, Qb, Kb, Vb, ock, ocv);
  attn_kernel<<<512, 256, 0, stream>>>(Qb, Kb, Vb, abuf);
  out_gemm_kernel<<<dim3(kT / 128, kHid / 128), 256, 0, stream>>>(abuf, Wo, out);
}